// Round 2
// baseline (1211.849 us; speedup 1.0000x reference)
//
#include <hip/hip_runtime.h>

#define B_ 4
#define W_ 1024
#define C_ 1024
#define H_ 16
#define D_ 64
#define K_ 3

// ---------------------------------------------------------------------------
// GEMM: out[m,n] = sum_k A[m,k]*Wt[n,k] + bias[n]
// A: (M,K) row-major, Wt: (N,K) row-major (i.e. out = A @ Wt^T + bias)
// 64x64 tile, BK=16, 256 threads, 4x4 per thread.
// ---------------------------------------------------------------------------
__global__ __launch_bounds__(256)
void gemm_bias_kernel(const float* __restrict__ A, const float* __restrict__ Wt,
                      const float* __restrict__ bias, float* __restrict__ out,
                      int M, int N, int K) {
  __shared__ float As[16][68];  // [k][m]
  __shared__ float Bs[16][68];  // [k][n]
  const int tid = threadIdx.x;
  const int bm = blockIdx.y * 64;
  const int bn = blockIdx.x * 64;
  const int tx = tid & 15, ty = tid >> 4;
  const int lr = tid >> 2;        // 0..63 tile row
  const int lk = (tid & 3) << 2;  // 0,4,8,12
  const float* ap = A + (size_t)(bm + lr) * K + lk;
  const float* bp = Wt + (size_t)(bn + lr) * K + lk;
  float acc[4][4] = {};
  for (int k0 = 0; k0 < K; k0 += 16) {
    float4 a4 = *(const float4*)(ap + k0);
    float4 b4 = *(const float4*)(bp + k0);
    __syncthreads();  // protect previous iteration's reads
    As[lk + 0][lr] = a4.x; As[lk + 1][lr] = a4.y;
    As[lk + 2][lr] = a4.z; As[lk + 3][lr] = a4.w;
    Bs[lk + 0][lr] = b4.x; Bs[lk + 1][lr] = b4.y;
    Bs[lk + 2][lr] = b4.z; Bs[lk + 3][lr] = b4.w;
    __syncthreads();
#pragma unroll
    for (int kk = 0; kk < 16; ++kk) {
      float4 av = *(const float4*)&As[kk][ty * 4];
      float4 bv = *(const float4*)&Bs[kk][tx * 4];
      float ar[4] = {av.x, av.y, av.z, av.w};
      float br[4] = {bv.x, bv.y, bv.z, bv.w};
#pragma unroll
      for (int r = 0; r < 4; ++r)
#pragma unroll
        for (int c = 0; c < 4; ++c)
          acc[r][c] = fmaf(ar[r], br[c], acc[r][c]);
    }
  }
  const float4 bb = *(const float4*)(bias + bn + tx * 4);
  const float bsc[4] = {bb.x, bb.y, bb.z, bb.w};
#pragma unroll
  for (int r = 0; r < 4; ++r) {
    const int row = bm + ty * 4 + r;
    float4 o4;
    o4.x = acc[r][0] + bsc[0];
    o4.y = acc[r][1] + bsc[1];
    o4.z = acc[r][2] + bsc[2];
    o4.w = acc[r][3] + bsc[3];
    *(float4*)(out + (size_t)row * N + bn + tx * 4) = o4;
  }
}

// ---------------------------------------------------------------------------
// Causal depthwise conv, K=3, left zero pad:
// out[b,w,c] = in[b,w-2,c]*cw[c,0] + in[b,w-1,c]*cw[c,1] + in[b,w,c]*cw[c,2] + cb[c]
// ---------------------------------------------------------------------------
__global__ __launch_bounds__(256)
void dwconv_kernel(const float* __restrict__ in, const float* __restrict__ cw,
                   const float* __restrict__ cb, float* __restrict__ out) {
  const int idx = blockIdx.x * 256 + threadIdx.x;  // over B*W*(C/4)
  const int c4 = (idx & (C_ / 4 - 1)) << 2;
  const int bw = idx >> 8;  // / (C_/4)
  const int w = bw & (W_ - 1);
  const float4 z = {0.f, 0.f, 0.f, 0.f};
  const float* base = in + (size_t)bw * C_ + c4;
  float4 x2 = *(const float4*)(base);
  float4 x1 = (w >= 1) ? *(const float4*)(base - C_) : z;
  float4 x0 = (w >= 2) ? *(const float4*)(base - 2 * C_) : z;
  float4 r;
  const float* xs0 = &x0.x; const float* xs1 = &x1.x; const float* xs2 = &x2.x;
  float* rs = &r.x;
#pragma unroll
  for (int j = 0; j < 4; ++j) {
    const int c = c4 + j;
    rs[j] = xs0[j] * cw[c * K_ + 0] + xs1[j] * cw[c * K_ + 1] +
            xs2[j] * cw[c * K_ + 2] + cb[c];
  }
  *(float4*)(out + (size_t)bw * C_ + c4) = r;
}

// ---------------------------------------------------------------------------
// Fused skewed attention per (b,h), flash-style over 64x64 tiles.
// S[i,j] = (q_i . k_j + q_j . er[:,i]) / 32 ; softmax over j ; O = P V.
// Output written directly into (B, W, C) layout.
// ---------------------------------------------------------------------------
__global__ __launch_bounds__(256)
void attn_kernel(const float* __restrict__ q, const float* __restrict__ k,
                 const float* __restrict__ v, const float* __restrict__ er,
                 float* __restrict__ o) {
  __shared__ float sQ[64][68];    // [i][d]
  __shared__ float sEr[64][68];   // [d][i]   (er columns for this query tile)
  __shared__ float sKt[64][68];   // [d][j]
  __shared__ float sQjt[64][68];  // [d][j]   (q rows at key positions)
  __shared__ float sV[64][68];    // [j][d]
  __shared__ float sP[64][68];    // [i][j]
  const int tid = threadIdx.x;
  const int bh = blockIdx.y;
  const int b = bh >> 4;   // / H_
  const int h = bh & 15;   // % H_
  const int i0 = blockIdx.x * 64;
  const int tx = tid & 15, ty = tid >> 4;
  const int lr = tid & 63;           // loader row
  const int lc = (tid >> 6) * 16;    // loader 16-col chunk

  {
    const float* qp = q + ((size_t)(b * W_) + i0 + lr) * C_ + h * D_ + lc;
    const float* ep = er + (size_t)lr * W_ + i0 + lc;
#pragma unroll
    for (int t = 0; t < 4; ++t) {
      *(float4*)&sQ[lr][lc + t * 4] = *(const float4*)(qp + t * 4);
      *(float4*)&sEr[lr][lc + t * 4] = *(const float4*)(ep + t * 4);
    }
  }

  float m[4], l[4], acc[4][4];
#pragma unroll
  for (int r = 0; r < 4; ++r) {
    m[r] = -1e30f; l[r] = 0.f;
#pragma unroll
    for (int c = 0; c < 4; ++c) acc[r][c] = 0.f;
  }

  for (int jt = 0; jt < W_ / 64; ++jt) {
    const int j0 = jt * 64;
    __syncthreads();  // previous PV / initial Q,Er loads complete
    {
      const float* kp = k + ((size_t)(b * W_) + j0 + lr) * C_ + h * D_ + lc;
      const float* qjp = q + ((size_t)(b * W_) + j0 + lr) * C_ + h * D_ + lc;
      const float* vp = v + ((size_t)(b * W_) + j0 + lr) * C_ + h * D_ + lc;
#pragma unroll
      for (int t = 0; t < 4; ++t) {
        float4 kv = *(const float4*)(kp + t * 4);
        sKt[lc + t * 4 + 0][lr] = kv.x; sKt[lc + t * 4 + 1][lr] = kv.y;
        sKt[lc + t * 4 + 2][lr] = kv.z; sKt[lc + t * 4 + 3][lr] = kv.w;
        float4 qv = *(const float4*)(qjp + t * 4);
        sQjt[lc + t * 4 + 0][lr] = qv.x; sQjt[lc + t * 4 + 1][lr] = qv.y;
        sQjt[lc + t * 4 + 2][lr] = qv.z; sQjt[lc + t * 4 + 3][lr] = qv.w;
        *(float4*)&sV[lr][lc + t * 4] = *(const float4*)(vp + t * 4);
      }
    }
    __syncthreads();

    float s[4][4] = {};
#pragma unroll
    for (int d = 0; d < 64; ++d) {
      float aq[4];
#pragma unroll
      for (int r = 0; r < 4; ++r) aq[r] = sQ[ty * 4 + r][d];
      float4 aev = *(const float4*)&sEr[d][ty * 4];
      float4 bkv = *(const float4*)&sKt[d][tx * 4];
      float4 bqv = *(const float4*)&sQjt[d][tx * 4];
      float ae[4] = {aev.x, aev.y, aev.z, aev.w};
      float bk[4] = {bkv.x, bkv.y, bkv.z, bkv.w};
      float bq[4] = {bqv.x, bqv.y, bqv.z, bqv.w};
#pragma unroll
      for (int r = 0; r < 4; ++r)
#pragma unroll
        for (int c = 0; c < 4; ++c)
          s[r][c] = fmaf(aq[r], bk[c], fmaf(ae[r], bq[c], s[r][c]));
    }

    const float inv = 0.03125f;  // 1/sqrt(C) = 1/32
#pragma unroll
    for (int r = 0; r < 4; ++r) {
#pragma unroll
      for (int c = 0; c < 4; ++c) s[r][c] *= inv;
      float mx = fmaxf(fmaxf(s[r][0], s[r][1]), fmaxf(s[r][2], s[r][3]));
      mx = fmaxf(mx, __shfl_xor(mx, 1));
      mx = fmaxf(mx, __shfl_xor(mx, 2));
      mx = fmaxf(mx, __shfl_xor(mx, 4));
      mx = fmaxf(mx, __shfl_xor(mx, 8));
      const float mn = fmaxf(m[r], mx);
      const float sc = __expf(m[r] - mn);
      float rs = 0.f;
#pragma unroll
      for (int c = 0; c < 4; ++c) { s[r][c] = __expf(s[r][c] - mn); rs += s[r][c]; }
      rs += __shfl_xor(rs, 1);
      rs += __shfl_xor(rs, 2);
      rs += __shfl_xor(rs, 4);
      rs += __shfl_xor(rs, 8);
      l[r] = l[r] * sc + rs;
      m[r] = mn;
#pragma unroll
      for (int c = 0; c < 4; ++c) acc[r][c] *= sc;
    }

#pragma unroll
    for (int r = 0; r < 4; ++r)
      *(float4*)&sP[ty * 4 + r][tx * 4] =
          make_float4(s[r][0], s[r][1], s[r][2], s[r][3]);
    __syncthreads();

#pragma unroll
    for (int j = 0; j < 64; ++j) {
      float ap_[4];
#pragma unroll
      for (int r = 0; r < 4; ++r) ap_[r] = sP[ty * 4 + r][j];
      float4 bvv = *(const float4*)&sV[j][tx * 4];
      float bv[4] = {bvv.x, bvv.y, bvv.z, bvv.w};
#pragma unroll
      for (int r = 0; r < 4; ++r)
#pragma unroll
        for (int c = 0; c < 4; ++c)
          acc[r][c] = fmaf(ap_[r], bv[c], acc[r][c]);
    }
  }

#pragma unroll
  for (int r = 0; r < 4; ++r) {
    const float invl = 1.f / l[r];
    float4 o4 = make_float4(acc[r][0] * invl, acc[r][1] * invl,
                            acc[r][2] * invl, acc[r][3] * invl);
    *(float4*)(o + ((size_t)(b * W_) + i0 + ty * 4 + r) * C_ + h * D_ + tx * 4) = o4;
  }
}

// ---------------------------------------------------------------------------
extern "C" void kernel_launch(void* const* d_in, const int* in_sizes, int n_in,
                              void* d_out, int out_size, void* d_ws, size_t ws_size,
                              hipStream_t stream) {
  (void)in_sizes; (void)n_in; (void)out_size; (void)ws_size;
  const float* x   = (const float*)d_in[0];
  const float* qW  = (const float*)d_in[1];
  const float* qb  = (const float*)d_in[2];
  const float* qcw = (const float*)d_in[3];
  const float* qcb = (const float*)d_in[4];
  const float* kW  = (const float*)d_in[5];
  const float* kb  = (const float*)d_in[6];
  const float* kcw = (const float*)d_in[7];
  const float* kcb = (const float*)d_in[8];
  const float* vW  = (const float*)d_in[9];
  const float* vb  = (const float*)d_in[10];
  const float* vcw = (const float*)d_in[11];
  const float* vcb = (const float*)d_in[12];
  const float* oW  = (const float*)d_in[13];
  const float* ob  = (const float*)d_in[14];
  const float* er  = (const float*)d_in[15];
  float* out = (float*)d_out;

  const size_t NE = (size_t)B_ * W_ * C_;  // 4,194,304 elems (16 MB f32)
  float* ws  = (float*)d_ws;
  float* yq  = ws + 0 * NE;  // pre-conv q
  float* yk  = ws + 1 * NE;  // pre-conv k
  float* yv  = ws + 2 * NE;  // pre-conv v
  float* qc  = ws + 3 * NE;  // post-conv q
  float* kc  = yq;           // post-conv k (reuses yq: dead after its conv)
  float* vc  = yk;           // post-conv v (reuses yk)
  float* oat = yv;           // attention out (reuses yv)

  const int M = B_ * W_;
  dim3 gg(C_ / 64, M / 64);  // (16, 64)
  gemm_bias_kernel<<<gg, 256, 0, stream>>>(x, qW, qb, yq, M, C_, C_);
  gemm_bias_kernel<<<gg, 256, 0, stream>>>(x, kW, kb, yk, M, C_, C_);
  gemm_bias_kernel<<<gg, 256, 0, stream>>>(x, vW, vb, yv, M, C_, C_);

  const int nconv = B_ * W_ * (C_ / 4) / 256;  // 4096 blocks
  dwconv_kernel<<<nconv, 256, 0, stream>>>(yq, qcw, qcb, qc);
  dwconv_kernel<<<nconv, 256, 0, stream>>>(yk, kcw, kcb, kc);
  dwconv_kernel<<<nconv, 256, 0, stream>>>(yv, vcw, vcb, vc);

  dim3 ga(W_ / 64, B_ * H_);  // (16, 64)
  attn_kernel<<<ga, 256, 0, stream>>>(qc, kc, vc, er, oat);

  gemm_bias_kernel<<<gg, 256, 0, stream>>>(oat, oW, ob, out, M, C_, C_);
}

// Round 3
// 381.737 us; speedup vs baseline: 3.1746x; 3.1746x over previous
//
#include <hip/hip_runtime.h>

#define B_ 4
#define W_ 1024
#define C_ 1024
#define H_ 16
#define D_ 64

typedef __attribute__((ext_vector_type(8))) short short8;
typedef __attribute__((ext_vector_type(4))) float f32x4;

__device__ __forceinline__ unsigned short f2b(float f) {
  unsigned u = __builtin_bit_cast(unsigned, f);
  unsigned r = (u + 0x7fffu + ((u >> 16) & 1u)) >> 16;
  return (unsigned short)r;
}
__device__ __forceinline__ float b2f(short b) {
  return __builtin_bit_cast(float, ((unsigned)(unsigned short)b) << 16);
}

// ---------------------------------------------------------------------------
// f32 -> bf16 cast, 8 elems/thread
// ---------------------------------------------------------------------------
__global__ __launch_bounds__(256)
void cast_bf16_kernel(const float* __restrict__ in, short* __restrict__ out, int n8) {
  int i = blockIdx.x * 256 + threadIdx.x;
  if (i >= n8) return;
  const float4* p = (const float4*)in + (size_t)i * 2;
  float4 a = p[0], b = p[1];
  short8 r;
  r[0] = f2b(a.x); r[1] = f2b(a.y); r[2] = f2b(a.z); r[3] = f2b(a.w);
  r[4] = f2b(b.x); r[5] = f2b(b.y); r[6] = f2b(b.z); r[7] = f2b(b.w);
  *((short8*)out + i) = r;
}

// er (D, W) f32 -> ert (W, D) bf16
__global__ __launch_bounds__(256)
void transpose_er_kernel(const float* __restrict__ er, short* __restrict__ ert) {
  int i = blockIdx.x * 256 + threadIdx.x;  // D * W/4 = 16384
  int d = i >> 8;
  int w4 = (i & 255) << 2;
  float4 v = *(const float4*)(er + (size_t)d * W_ + w4);
  ert[(size_t)(w4 + 0) * D_ + d] = f2b(v.x);
  ert[(size_t)(w4 + 1) * D_ + d] = f2b(v.y);
  ert[(size_t)(w4 + 2) * D_ + d] = f2b(v.z);
  ert[(size_t)(w4 + 3) * D_ + d] = f2b(v.w);
}

// vc (B,W,C) bf16 -> vt (B*H, D, W) bf16
__global__ __launch_bounds__(256)
void transpose_v_kernel(const short* __restrict__ vc, short* __restrict__ vt) {
  __shared__ short t[64][72];
  const int bh = blockIdx.y, w0 = blockIdx.x * 64;
  const int b = bh >> 4, h = bh & 15;
  const int tid = threadIdx.x;
  for (int c = tid; c < 512; c += 256) {
    int w = c >> 3, dg = c & 7;
    short8 v = *(const short8*)(vc + ((size_t)(b * W_ + w0 + w)) * C_ + h * 64 + dg * 8);
#pragma unroll
    for (int e = 0; e < 8; ++e) t[dg * 8 + e][w] = v[e];
  }
  __syncthreads();
  for (int c = tid; c < 512; c += 256) {
    int d = c >> 3, wg = c & 7;
    short8 o = *(short8*)&t[d][wg * 8];
    *(short8*)(vt + ((size_t)(bh * 64 + d)) * W_ + w0 + wg * 8) = o;
  }
}

// ---------------------------------------------------------------------------
// MFMA GEMM: out = A(M,K)bf16 @ Wt(N,K)bf16^T + bias(f32). 128x128 tile, BK=64.
// ---------------------------------------------------------------------------
template <int OUTF32>
__global__ __launch_bounds__(256)
void gemm_bf16_kernel(const short* __restrict__ A, const short* __restrict__ Wt,
                      const float* __restrict__ bias, void* __restrict__ outv,
                      int M, int N, int K) {
  __shared__ short sA[128][72];
  __shared__ short sB[128][72];
  const int tid = threadIdx.x;
  const int bm = blockIdx.y * 128, bn = blockIdx.x * 128;
  const int wv = tid >> 6, lane = tid & 63;
  const int wr = (wv >> 1) * 64, wc = (wv & 1) * 64;
  const int l15 = lane & 15, l4 = lane >> 4;
  f32x4 acc[4][4];
#pragma unroll
  for (int mf = 0; mf < 4; ++mf)
#pragma unroll
    for (int nf = 0; nf < 4; ++nf) acc[mf][nf] = (f32x4){0.f, 0.f, 0.f, 0.f};

  for (int k0 = 0; k0 < K; k0 += 64) {
    __syncthreads();
#pragma unroll
    for (int c = tid; c < 1024; c += 256) {
      int row = c >> 3, kg = c & 7;
      *(short8*)&sA[row][kg * 8] = *(const short8*)(A + (size_t)(bm + row) * K + k0 + kg * 8);
      *(short8*)&sB[row][kg * 8] = *(const short8*)(Wt + (size_t)(bn + row) * K + k0 + kg * 8);
    }
    __syncthreads();
#pragma unroll
    for (int ks = 0; ks < 2; ++ks) {
      short8 af[4], bf[4];
#pragma unroll
      for (int mf = 0; mf < 4; ++mf) af[mf] = *(short8*)&sA[wr + mf * 16 + l15][ks * 32 + l4 * 8];
#pragma unroll
      for (int nf = 0; nf < 4; ++nf) bf[nf] = *(short8*)&sB[wc + nf * 16 + l15][ks * 32 + l4 * 8];
#pragma unroll
      for (int mf = 0; mf < 4; ++mf)
#pragma unroll
        for (int nf = 0; nf < 4; ++nf)
          acc[mf][nf] = __builtin_amdgcn_mfma_f32_16x16x32_bf16(af[mf], bf[nf], acc[mf][nf], 0, 0, 0);
    }
  }
#pragma unroll
  for (int mf = 0; mf < 4; ++mf) {
#pragma unroll
    for (int nf = 0; nf < 4; ++nf) {
      const int n = bn + wc + nf * 16 + l15;
      const float bs = bias[n];
#pragma unroll
      for (int r = 0; r < 4; ++r) {
        const int m = bm + wr + mf * 16 + l4 * 4 + r;
        const float v = acc[mf][nf][r] + bs;
        if (OUTF32) ((float*)outv)[(size_t)m * N + n] = v;
        else        ((short*)outv)[(size_t)m * N + n] = (short)f2b(v);
      }
    }
  }
}

// ---------------------------------------------------------------------------
// Causal depthwise conv K=3, bf16 in/out
// ---------------------------------------------------------------------------
__global__ __launch_bounds__(256)
void dwconv_kernel(const short* __restrict__ in, const float* __restrict__ cw,
                   const float* __restrict__ cb, short* __restrict__ out) {
  const int idx = blockIdx.x * 256 + threadIdx.x;  // B*W*(C/8)
  const int c8 = (idx & (C_ / 8 - 1)) << 3;
  const int bw = idx >> 7;
  const int w = bw & (W_ - 1);
  const short* base = in + (size_t)bw * C_ + c8;
  short8 x2 = *(const short8*)base;
  short8 x1, x0;
  if (w >= 1) x1 = *(const short8*)(base - C_); else { for (int j = 0; j < 8; ++j) x1[j] = 0; }
  if (w >= 2) x0 = *(const short8*)(base - 2 * C_); else { for (int j = 0; j < 8; ++j) x0[j] = 0; }
  short8 r;
#pragma unroll
  for (int j = 0; j < 8; ++j) {
    const int c = c8 + j;
    float acc = b2f(x0[j]) * cw[c * 3 + 0] + b2f(x1[j]) * cw[c * 3 + 1] +
                b2f(x2[j]) * cw[c * 3 + 2] + cb[c];
    r[j] = (short)f2b(acc);
  }
  *(short8*)(out + (size_t)bw * C_ + c8) = r;
}

// ---------------------------------------------------------------------------
// Fused skewed attention, MFMA. Per (b,h) x 64-query tile, 4 waves (16 rows each).
// S = [Q | ErT](64x128) x [K | Qj](64x128)^T over K=128; online softmax; O = P V.
// ---------------------------------------------------------------------------
__global__ __launch_bounds__(256)
void attn_mfma_kernel(const short* __restrict__ q, const short* __restrict__ k,
                      const short* __restrict__ vt, const short* __restrict__ ert,
                      short* __restrict__ o) {
  __shared__ short sQE[64][136];  // [i][0:64 Q | 64:128 ErT]
  __shared__ short sKQ[64][136];  // [j][0:64 K | 64:128 Qj]
  __shared__ short sVt[64][72];   // [d][j]
  __shared__ short sP[64][72];    // [i][j]
  const int tid = threadIdx.x;
  const int bh = blockIdx.y, b = bh >> 4, h = bh & 15;
  const int i0 = blockIdx.x * 64;
  const int wv = tid >> 6, lane = tid & 63;
  const int l15 = lane & 15, l4 = lane >> 4;
  const size_t bW = (size_t)b * W_;

  for (int c = tid; c < 512; c += 256) {
    int row = c >> 3, dg = c & 7;
    *(short8*)&sQE[row][dg * 8] = *(const short8*)(q + (bW + i0 + row) * C_ + h * 64 + dg * 8);
    *(short8*)&sQE[row][64 + dg * 8] = *(const short8*)(ert + (size_t)(i0 + row) * 64 + dg * 8);
  }
  __syncthreads();
  short8 aQ[4];  // hoisted A-fragments (Q|ErT rows of this wave)
#pragma unroll
  for (int ks = 0; ks < 4; ++ks) aQ[ks] = *(short8*)&sQE[wv * 16 + l15][ks * 32 + l4 * 8];

  float m_[4], l_[4];
  f32x4 accO[4];
#pragma unroll
  for (int r = 0; r < 4; ++r) { m_[r] = -1e30f; l_[r] = 0.f; }
#pragma unroll
  for (int nf = 0; nf < 4; ++nf) accO[nf] = (f32x4){0.f, 0.f, 0.f, 0.f};

  for (int jt = 0; jt < 16; ++jt) {
    const int j0 = jt * 64;
    __syncthreads();  // previous PV reads done before overwriting sKQ/sVt
    for (int c = tid; c < 512; c += 256) {
      int row = c >> 3, dg = c & 7;
      *(short8*)&sKQ[row][dg * 8] = *(const short8*)(k + (bW + j0 + row) * C_ + h * 64 + dg * 8);
      *(short8*)&sKQ[row][64 + dg * 8] = *(const short8*)(q + (bW + j0 + row) * C_ + h * 64 + dg * 8);
      *(short8*)&sVt[row][dg * 8] = *(const short8*)(vt + ((size_t)bh * 64 + row) * W_ + j0 + dg * 8);
    }
    __syncthreads();

    f32x4 s[4];
#pragma unroll
    for (int nf = 0; nf < 4; ++nf) s[nf] = (f32x4){0.f, 0.f, 0.f, 0.f};
#pragma unroll
    for (int ks = 0; ks < 4; ++ks)
#pragma unroll
      for (int nf = 0; nf < 4; ++nf) {
        short8 bF = *(short8*)&sKQ[nf * 16 + l15][ks * 32 + l4 * 8];
        s[nf] = __builtin_amdgcn_mfma_f32_16x16x32_bf16(aQ[ks], bF, s[nf], 0, 0, 0);
      }

    const float SC = 0.03125f;  // 1/sqrt(C)
#pragma unroll
    for (int r = 0; r < 4; ++r) {
      float v0 = s[0][r] * SC, v1 = s[1][r] * SC, v2 = s[2][r] * SC, v3 = s[3][r] * SC;
      float mx = fmaxf(fmaxf(v0, v1), fmaxf(v2, v3));
      mx = fmaxf(mx, __shfl_xor(mx, 1));
      mx = fmaxf(mx, __shfl_xor(mx, 2));
      mx = fmaxf(mx, __shfl_xor(mx, 4));
      mx = fmaxf(mx, __shfl_xor(mx, 8));
      const float mn = fmaxf(m_[r], mx);
      const float sc = __expf(m_[r] - mn);
      float p0 = __expf(v0 - mn), p1 = __expf(v1 - mn);
      float p2 = __expf(v2 - mn), p3 = __expf(v3 - mn);
      float rs = p0 + p1 + p2 + p3;
      rs += __shfl_xor(rs, 1);
      rs += __shfl_xor(rs, 2);
      rs += __shfl_xor(rs, 4);
      rs += __shfl_xor(rs, 8);
      l_[r] = l_[r] * sc + rs;
      m_[r] = mn;
#pragma unroll
      for (int nf = 0; nf < 4; ++nf) accO[nf][r] *= sc;
      const int il = wv * 16 + l4 * 4 + r;
      sP[il][l15]      = (short)f2b(p0);
      sP[il][16 + l15] = (short)f2b(p1);
      sP[il][32 + l15] = (short)f2b(p2);
      sP[il][48 + l15] = (short)f2b(p3);
    }
    __syncthreads();

#pragma unroll
    for (int ks = 0; ks < 2; ++ks) {
      short8 aP = *(short8*)&sP[wv * 16 + l15][ks * 32 + l4 * 8];
#pragma unroll
      for (int nf = 0; nf < 4; ++nf) {
        short8 bV = *(short8*)&sVt[nf * 16 + l15][ks * 32 + l4 * 8];
        accO[nf] = __builtin_amdgcn_mfma_f32_16x16x32_bf16(aP, bV, accO[nf], 0, 0, 0);
      }
    }
  }

#pragma unroll
  for (int r = 0; r < 4; ++r) {
    const float inv = 1.f / l_[r];
    const int i = i0 + wv * 16 + l4 * 4 + r;
#pragma unroll
    for (int nf = 0; nf < 4; ++nf) {
      const int d = nf * 16 + l15;
      o[(bW + i) * C_ + h * 64 + d] = (short)f2b(accO[nf][r] * inv);
    }
  }
}

// ---------------------------------------------------------------------------
extern "C" void kernel_launch(void* const* d_in, const int* in_sizes, int n_in,
                              void* d_out, int out_size, void* d_ws, size_t ws_size,
                              hipStream_t stream) {
  (void)in_sizes; (void)n_in; (void)out_size; (void)ws_size;
  const float* x   = (const float*)d_in[0];
  const float* qW  = (const float*)d_in[1];
  const float* qb  = (const float*)d_in[2];
  const float* qcw = (const float*)d_in[3];
  const float* qcb = (const float*)d_in[4];
  const float* kW  = (const float*)d_in[5];
  const float* kb  = (const float*)d_in[6];
  const float* kcw = (const float*)d_in[7];
  const float* kcb = (const float*)d_in[8];
  const float* vW  = (const float*)d_in[9];
  const float* vb  = (const float*)d_in[10];
  const float* vcw = (const float*)d_in[11];
  const float* vcb = (const float*)d_in[12];
  const float* oW  = (const float*)d_in[13];
  const float* ob  = (const float*)d_in[14];
  const float* er  = (const float*)d_in[15];
  float* out = (float*)d_out;

  const size_t NE = (size_t)B_ * W_ * C_;   // 4,194,304
  const size_t NW = (size_t)C_ * C_;        // 1,048,576
  short* ws  = (short*)d_ws;
  short* xh  = ws;
  short* qWh = xh + NE;
  short* kWh = qWh + NW;
  short* vWh = kWh + NW;
  short* oWh = vWh + NW;
  short* ertb = oWh + NW;            // W*D = 65536
  short* bufA = ertb + (size_t)W_ * D_;  // yq -> oat
  short* bufB = bufA + NE;           // yk -> vt
  short* bufC = bufB + NE;           // yv
  short* bufD = bufC + NE;           // qc
  short* bufE = bufD + NE;           // kc
  short* bufF = bufE + NE;           // vc
  // total = 64.125 MB (< the 67.1 MB round-2 proved available)

  cast_bf16_kernel<<<2048, 256, 0, stream>>>(x, xh, (int)(NE / 8));
  cast_bf16_kernel<<<512, 256, 0, stream>>>(qW, qWh, (int)(NW / 8));
  cast_bf16_kernel<<<512, 256, 0, stream>>>(kW, kWh, (int)(NW / 8));
  cast_bf16_kernel<<<512, 256, 0, stream>>>(vW, vWh, (int)(NW / 8));
  cast_bf16_kernel<<<512, 256, 0, stream>>>(oW, oWh, (int)(NW / 8));
  transpose_er_kernel<<<64, 256, 0, stream>>>(er, ertb);

  const int M = B_ * W_;
  dim3 gg(C_ / 128, M / 128);  // (8, 32)
  gemm_bf16_kernel<0><<<gg, 256, 0, stream>>>(xh, qWh, qb, bufA, M, C_, C_);
  gemm_bf16_kernel<0><<<gg, 256, 0, stream>>>(xh, kWh, kb, bufB, M, C_, C_);
  gemm_bf16_kernel<0><<<gg, 256, 0, stream>>>(xh, vWh, vb, bufC, M, C_, C_);

  const int nconv = B_ * W_ * (C_ / 8) / 256;  // 2048
  dwconv_kernel<<<nconv, 256, 0, stream>>>(bufA, qcw, qcb, bufD);
  dwconv_kernel<<<nconv, 256, 0, stream>>>(bufB, kcw, kcb, bufE);
  dwconv_kernel<<<nconv, 256, 0, stream>>>(bufC, vcw, vcb, bufF);

  dim3 gt(W_ / 64, B_ * H_);  // (16, 64)
  transpose_v_kernel<<<gt, 256, 0, stream>>>(bufF, bufB);  // vt into bufB

  attn_mfma_kernel<<<gt, 256, 0, stream>>>(bufD, bufE, bufB, ertb, bufA);  // oat into bufA

  gemm_bf16_kernel<1><<<gg, 256, 0, stream>>>(bufA, oWh, ob, out, M, C_, C_);
}

// Round 4
// 282.410 us; speedup vs baseline: 4.2911x; 1.3517x over previous
//
#include <hip/hip_runtime.h>

#define B_ 4
#define W_ 1024
#define C_ 1024
#define H_ 16
#define D_ 64

typedef __attribute__((ext_vector_type(8))) short short8;
typedef __attribute__((ext_vector_type(4))) float f32x4;

__device__ __forceinline__ unsigned short f2b(float f) {
  unsigned u = __builtin_bit_cast(unsigned, f);
  unsigned r = (u + 0x7fffu + ((u >> 16) & 1u)) >> 16;
  return (unsigned short)r;
}
__device__ __forceinline__ float b2f(short b) {
  return __builtin_bit_cast(float, ((unsigned)(unsigned short)b) << 16);
}
__device__ __forceinline__ unsigned pk2(float a, float b) {
  return (unsigned)f2b(a) | ((unsigned)f2b(b) << 16);
}

// async global->LDS, 16B per lane. dst must be wave-uniform base + lane*16.
typedef __attribute__((address_space(1))) void GV;
typedef __attribute__((address_space(3))) void LV;
__device__ __forceinline__ void gl16(const short* g, short* l) {
  __builtin_amdgcn_global_load_lds((GV*)g, (LV*)l, 16, 0, 0);
}

// ---------------------------------------------------------------------------
// f32 -> bf16 cast, 8 elems/thread
// ---------------------------------------------------------------------------
__global__ __launch_bounds__(256)
void cast_bf16_kernel(const float* __restrict__ in, short* __restrict__ out, int n8) {
  int i = blockIdx.x * 256 + threadIdx.x;
  if (i >= n8) return;
  const float4* p = (const float4*)in + (size_t)i * 2;
  float4 a = p[0], b = p[1];
  short8 r;
  r[0] = f2b(a.x); r[1] = f2b(a.y); r[2] = f2b(a.z); r[3] = f2b(a.w);
  r[4] = f2b(b.x); r[5] = f2b(b.y); r[6] = f2b(b.z); r[7] = f2b(b.w);
  *((short8*)out + i) = r;
}

// 4 weight matrices in one dispatch (blockIdx.y selects)
__global__ __launch_bounds__(256)
void cast4_kernel(const float* __restrict__ a0, const float* __restrict__ a1,
                  const float* __restrict__ a2, const float* __restrict__ a3,
                  short* __restrict__ d0, short* __restrict__ d1,
                  short* __restrict__ d2, short* __restrict__ d3) {
  const float* s; short* d;
  switch (blockIdx.y) {
    case 0: s = a0; d = d0; break;
    case 1: s = a1; d = d1; break;
    case 2: s = a2; d = d2; break;
    default: s = a3; d = d3; break;
  }
  int i = blockIdx.x * 256 + threadIdx.x;
  const float4* p = (const float4*)s + (size_t)i * 2;
  float4 a = p[0], b = p[1];
  short8 r;
  r[0] = f2b(a.x); r[1] = f2b(a.y); r[2] = f2b(a.z); r[3] = f2b(a.w);
  r[4] = f2b(b.x); r[5] = f2b(b.y); r[6] = f2b(b.z); r[7] = f2b(b.w);
  *((short8*)d + i) = r;
}

// er (D, W) f32 -> ert (W, D) bf16
__global__ __launch_bounds__(256)
void transpose_er_kernel(const float* __restrict__ er, short* __restrict__ ert) {
  int i = blockIdx.x * 256 + threadIdx.x;  // D * W/4 = 16384
  int d = i >> 8;
  int w4 = (i & 255) << 2;
  float4 v = *(const float4*)(er + (size_t)d * W_ + w4);
  ert[(size_t)(w4 + 0) * D_ + d] = f2b(v.x);
  ert[(size_t)(w4 + 1) * D_ + d] = f2b(v.y);
  ert[(size_t)(w4 + 2) * D_ + d] = f2b(v.z);
  ert[(size_t)(w4 + 3) * D_ + d] = f2b(v.w);
}

// vc (B,W,C) bf16 -> vt (B*H, D, W) bf16
__global__ __launch_bounds__(256)
void transpose_v_kernel(const short* __restrict__ vc, short* __restrict__ vt) {
  __shared__ short t[64][72];
  const int bh = blockIdx.y, w0 = blockIdx.x * 64;
  const int b = bh >> 4, h = bh & 15;
  const int tid = threadIdx.x;
  for (int c = tid; c < 512; c += 256) {
    int w = c >> 3, dg = c & 7;
    short8 v = *(const short8*)(vc + ((size_t)(b * W_ + w0 + w)) * C_ + h * 64 + dg * 8);
#pragma unroll
    for (int e = 0; e < 8; ++e) t[dg * 8 + e][w] = v[e];
  }
  __syncthreads();
  for (int c = tid; c < 512; c += 256) {
    int d = c >> 3, wg = c & 7;
    short8 o = *(short8*)&t[d][wg * 8];
    *(short8*)(vt + ((size_t)(bh * 64 + d)) * W_ + w0 + wg * 8) = o;
  }
}

// ---------------------------------------------------------------------------
// m97-style MFMA GEMM: out = A(M,K) @ Wt(N,K)^T + bias. 128x128 tile, BK=64,
// global_load_lds(16B) into linear LDS, 2-barrier K-loop.
// bias selected from 3 ptrs by n/1024 (for fused QKV); pass same ptr x3 else.
// ---------------------------------------------------------------------------
template <int OUTF32>
__global__ __launch_bounds__(256)
void gemm_bf16_v2(const short* __restrict__ A, const short* __restrict__ Wt,
                  const float* __restrict__ b0, const float* __restrict__ b1,
                  const float* __restrict__ b2, void* __restrict__ outv,
                  int M, int N, int K) {
  __shared__ short sA[128 * 64];
  __shared__ short sB[128 * 64];
  const int tid = threadIdx.x;
  const int bm = blockIdx.y * 128, bn = blockIdx.x * 128;
  const int wv = tid >> 6, lane = tid & 63;
  const int wr = (wv >> 1) * 64, wc = (wv & 1) * 64;
  const int l15 = lane & 15, l4 = lane >> 4;
  const int srow = tid >> 3;       // 0..31
  const int scs = (tid & 7) * 8;   // short offset in 64-col row
  const short* ga = A + (size_t)(bm + srow) * K + scs;
  const short* gb = Wt + (size_t)(bn + srow) * K + scs;
  short* la = sA + tid * 8;
  short* lb = sB + tid * 8;

  f32x4 acc[4][4];
#pragma unroll
  for (int mf = 0; mf < 4; ++mf)
#pragma unroll
    for (int nf = 0; nf < 4; ++nf) acc[mf][nf] = (f32x4){0.f, 0.f, 0.f, 0.f};

  for (int k0 = 0; k0 < K; k0 += 64) {
    __syncthreads();  // prior compute done before overwrite
#pragma unroll
    for (int i = 0; i < 4; ++i) {
      gl16(ga + (size_t)(i * 32) * K + k0, la + i * 2048);
      gl16(gb + (size_t)(i * 32) * K + k0, lb + i * 2048);
    }
    __syncthreads();  // compiler drains vmcnt before barrier
#pragma unroll
    for (int ks = 0; ks < 2; ++ks) {
      short8 af[4], bf[4];
#pragma unroll
      for (int mf = 0; mf < 4; ++mf)
        af[mf] = *(short8*)(sA + (wr + mf * 16 + l15) * 64 + ks * 32 + l4 * 8);
#pragma unroll
      for (int nf = 0; nf < 4; ++nf)
        bf[nf] = *(short8*)(sB + (wc + nf * 16 + l15) * 64 + ks * 32 + l4 * 8);
#pragma unroll
      for (int mf = 0; mf < 4; ++mf)
#pragma unroll
        for (int nf = 0; nf < 4; ++nf)
          acc[mf][nf] = __builtin_amdgcn_mfma_f32_16x16x32_bf16(af[mf], bf[nf], acc[mf][nf], 0, 0, 0);
    }
  }
#pragma unroll
  for (int mf = 0; mf < 4; ++mf) {
#pragma unroll
    for (int nf = 0; nf < 4; ++nf) {
      const int n = bn + wc + nf * 16 + l15;
      const float bs = (n < 1024) ? b0[n] : ((n < 2048) ? b1[n - 1024] : b2[n - 2048]);
#pragma unroll
      for (int r = 0; r < 4; ++r) {
        const int m = bm + wr + mf * 16 + l4 * 4 + r;
        const float v = acc[mf][nf][r] + bs;
        if (OUTF32) ((float*)outv)[(size_t)m * N + n] = v;
        else        ((short*)outv)[(size_t)m * N + n] = (short)f2b(v);
      }
    }
  }
}

// ---------------------------------------------------------------------------
// Causal depthwise conv K=3 over fused yqkv (B*W, 3C); blockIdx.y selects q/k/v
// ---------------------------------------------------------------------------
__global__ __launch_bounds__(256)
void dwconv3_kernel(const short* __restrict__ yqkv,
                    const float* __restrict__ qcw, const float* __restrict__ qcb,
                    const float* __restrict__ kcw, const float* __restrict__ kcb,
                    const float* __restrict__ vcw, const float* __restrict__ vcb,
                    short* __restrict__ qc, short* __restrict__ kc, short* __restrict__ vc) {
  const int t = blockIdx.y;
  const float* cw; const float* cb; short* out;
  if (t == 0) { cw = qcw; cb = qcb; out = qc; }
  else if (t == 1) { cw = kcw; cb = kcb; out = kc; }
  else { cw = vcw; cb = vcb; out = vc; }
  const int idx = blockIdx.x * 256 + threadIdx.x;  // over B*W*(C/8)
  const int c8 = (idx & (C_ / 8 - 1)) << 3;
  const int bw = idx >> 7;
  const int w = bw & (W_ - 1);
  const short* base = yqkv + (size_t)bw * (3 * C_) + t * C_ + c8;
  short8 x2 = *(const short8*)base;
  short8 x1, x0;
  if (w >= 1) x1 = *(const short8*)(base - 3 * C_); else { for (int j = 0; j < 8; ++j) x1[j] = 0; }
  if (w >= 2) x0 = *(const short8*)(base - 6 * C_); else { for (int j = 0; j < 8; ++j) x0[j] = 0; }
  short8 r;
#pragma unroll
  for (int j = 0; j < 8; ++j) {
    const int c = c8 + j;
    float acc = b2f(x0[j]) * cw[c * 3 + 0] + b2f(x1[j]) * cw[c * 3 + 1] +
                b2f(x2[j]) * cw[c * 3 + 2] + cb[c];
    r[j] = (short)f2b(acc);
  }
  *(short8*)(out + (size_t)bw * C_ + c8) = r;
}

// ---------------------------------------------------------------------------
// Fused skewed attention, swapped-S orientation.
// S^T[j][i] = K[j].Q[i] + Qj[j].Er[i]; lane owns one i => 2-shuffle softmax.
// 2-phase dbuf staging via global_load_lds; one barrier per tile.
// Output O written (B,W,C).
// ---------------------------------------------------------------------------
__global__ __launch_bounds__(256)
void attn_v2_kernel(const short* __restrict__ q, const short* __restrict__ k,
                    const short* __restrict__ vt, const short* __restrict__ ert,
                    short* __restrict__ o) {
  __shared__ short sK[2][64 * 64];
  __shared__ short sQj[2][64 * 64];
  __shared__ short sVt[2][64 * 64];
  __shared__ short sU[64 * 128];  // union: {sQ[64*64] | sE[64*64]} then sP[64][72]
  short* sQ = sU;
  short* sE = sU + 4096;
  short* sP = sU;

  const int tid = threadIdx.x;
  // T1 XCD swizzle: consecutive hw blocks (same XCD stride 8) -> same bh group
  const int wid = blockIdx.x;
  const int swz = (wid & 7) * 128 + (wid >> 3);
  const int bh = swz >> 4;        // 0..63
  const int qt = swz & 15;
  const int b = bh >> 4, h = bh & 15;
  const int i0 = qt * 64;
  const int wv = tid >> 6, lane = tid & 63;
  const int l15 = lane & 15, l4 = lane >> 4;
  const size_t bW = (size_t)b * W_;
  const int srow = tid >> 3;
  const int scs = (tid & 7) * 8;

  const short* qbase = q + bW * C_ + h * 64;
  const short* kbase = k + bW * C_ + h * 64;
  const short* vbase = vt + (size_t)bh * 64 * W_;

  // prologue stages: Q,Er for this tile; K,Qj,Vt for jt=0
  {
    const short* g;
    g = qbase + (size_t)(i0 + srow) * C_ + scs;
    gl16(g, sQ + tid * 8); gl16(g + (size_t)32 * C_, sQ + 2048 + tid * 8);
    g = ert + (size_t)(i0 + srow) * 64 + scs;
    gl16(g, sE + tid * 8); gl16(g + 32 * 64, sE + 2048 + tid * 8);
    g = kbase + (size_t)srow * C_ + scs;
    gl16(g, sK[0] + tid * 8); gl16(g + (size_t)32 * C_, sK[0] + 2048 + tid * 8);
    g = qbase + (size_t)srow * C_ + scs;
    gl16(g, sQj[0] + tid * 8); gl16(g + (size_t)32 * C_, sQj[0] + 2048 + tid * 8);
    g = vbase + (size_t)srow * W_ + scs;
    gl16(g, sVt[0] + tid * 8); gl16(g + (size_t)32 * W_, sVt[0] + 2048 + tid * 8);
  }
  __syncthreads();

  // hoist B-fragments (Q rows / Er rows of this wave's 16 queries)
  short8 bQ[2], bE[2];
#pragma unroll
  for (int ks = 0; ks < 2; ++ks) {
    bQ[ks] = *(short8*)(sQ + (wv * 16 + l15) * 64 + ks * 32 + l4 * 8);
    bE[ks] = *(short8*)(sE + (wv * 16 + l15) * 64 + ks * 32 + l4 * 8);
  }
  __syncthreads();  // all waves done reading sQ/sE before sP overwrites union

  float m_ = -1e30f, l_ = 0.f;
  f32x4 accO[4];
#pragma unroll
  for (int mf = 0; mf < 4; ++mf) accO[mf] = (f32x4){0.f, 0.f, 0.f, 0.f};
  const float SC = 0.03125f;  // 1/sqrt(C)

  for (int jt = 0; jt < 16; ++jt) {
    const int cur = jt & 1;
    if (jt < 15) {  // prefetch next tile; flies during this tile's compute
      const int j0n = (jt + 1) * 64;
      const short* g;
      g = kbase + (size_t)(j0n + srow) * C_ + scs;
      gl16(g, sK[cur ^ 1] + tid * 8); gl16(g + (size_t)32 * C_, sK[cur ^ 1] + 2048 + tid * 8);
      g = qbase + (size_t)(j0n + srow) * C_ + scs;
      gl16(g, sQj[cur ^ 1] + tid * 8); gl16(g + (size_t)32 * C_, sQj[cur ^ 1] + 2048 + tid * 8);
      g = vbase + (size_t)srow * W_ + j0n + scs;
      gl16(g, sVt[cur ^ 1] + tid * 8); gl16(g + (size_t)32 * W_, sVt[cur ^ 1] + 2048 + tid * 8);
    }

    // S^T: rows j (A-frags from sK/sQj), cols i (hoisted bQ/bE)
    f32x4 s[4];
#pragma unroll
    for (int mf = 0; mf < 4; ++mf) s[mf] = (f32x4){0.f, 0.f, 0.f, 0.f};
    __builtin_amdgcn_s_setprio(1);
#pragma unroll
    for (int mf = 0; mf < 4; ++mf) {
      const short* kp = sK[cur] + (mf * 16 + l15) * 64 + l4 * 8;
      const short* jp = sQj[cur] + (mf * 16 + l15) * 64 + l4 * 8;
      s[mf] = __builtin_amdgcn_mfma_f32_16x16x32_bf16(*(short8*)kp, bQ[0], s[mf], 0, 0, 0);
      s[mf] = __builtin_amdgcn_mfma_f32_16x16x32_bf16(*(short8*)(kp + 32), bQ[1], s[mf], 0, 0, 0);
      s[mf] = __builtin_amdgcn_mfma_f32_16x16x32_bf16(*(short8*)jp, bE[0], s[mf], 0, 0, 0);
      s[mf] = __builtin_amdgcn_mfma_f32_16x16x32_bf16(*(short8*)(jp + 32), bE[1], s[mf], 0, 0, 0);
    }
    __builtin_amdgcn_s_setprio(0);

    // online softmax over j (16 regs + lanes l4: 2 shuffles)
    float px = fmaxf(fmaxf(s[0][0], s[0][1]), fmaxf(s[0][2], s[0][3]));
#pragma unroll
    for (int mf = 1; mf < 4; ++mf)
      px = fmaxf(px, fmaxf(fmaxf(s[mf][0], s[mf][1]), fmaxf(s[mf][2], s[mf][3])));
    px = fmaxf(px, __shfl_xor(px, 16));
    px = fmaxf(px, __shfl_xor(px, 32));
    px *= SC;
    if (!__all(px <= m_ + 8.f)) {  // defer-max (T13): skip rescale on small growth
      const float mn = fmaxf(m_, px);
      const float sc = __expf(m_ - mn);
      l_ *= sc;
#pragma unroll
      for (int mf = 0; mf < 4; ++mf)
#pragma unroll
        for (int r = 0; r < 4; ++r) accO[mf][r] *= sc;
      m_ = mn;
    }
    float p[4][4];
    float rs = 0.f;
#pragma unroll
    for (int mf = 0; mf < 4; ++mf)
#pragma unroll
      for (int r = 0; r < 4; ++r) {
        p[mf][r] = __expf(__builtin_fmaf(s[mf][r], SC, -m_));
        rs += p[mf][r];
      }
    rs += __shfl_xor(rs, 16);
    rs += __shfl_xor(rs, 32);
    l_ += rs;

    // P rows i: lane holds 4 consecutive j per mf -> b64 packed writes
#pragma unroll
    for (int mf = 0; mf < 4; ++mf) {
      uint2 w2;
      w2.x = pk2(p[mf][0], p[mf][1]);
      w2.y = pk2(p[mf][2], p[mf][3]);
      *(uint2*)(sP + (wv * 16 + l15) * 72 + mf * 16 + l4 * 4) = w2;
    }

    // PV: O^T[d][i] += Vt[d][j-run] . P[i][j-run]   (same-wave sP rows; no barrier)
    short8 pf[2];
#pragma unroll
    for (int ks = 0; ks < 2; ++ks)
      pf[ks] = *(short8*)(sP + (wv * 16 + l15) * 72 + ks * 32 + l4 * 8);
    __builtin_amdgcn_s_setprio(1);
#pragma unroll
    for (int mf = 0; mf < 4; ++mf) {
      const short* vp = sVt[cur] + (mf * 16 + l15) * 64 + l4 * 8;
      accO[mf] = __builtin_amdgcn_mfma_f32_16x16x32_bf16(*(short8*)vp, pf[0], accO[mf], 0, 0, 0);
      accO[mf] = __builtin_amdgcn_mfma_f32_16x16x32_bf16(*(short8*)(vp + 32), pf[1], accO[mf], 0, 0, 0);
    }
    __builtin_amdgcn_s_setprio(0);

    __syncthreads();  // drains vmcnt (next tile landed) + lgkm; flips buffers
  }

  const float inv = 1.f / l_;
  const size_t orow = (bW + i0 + wv * 16 + l15) * C_ + h * 64;
#pragma unroll
  for (int mf = 0; mf < 4; ++mf) {
    uint2 w2;
    w2.x = pk2(accO[mf][0] * inv, accO[mf][1] * inv);
    w2.y = pk2(accO[mf][2] * inv, accO[mf][3] * inv);
    *(uint2*)(o + orow + mf * 16 + l4 * 4) = w2;
  }
}

// ---------------------------------------------------------------------------
extern "C" void kernel_launch(void* const* d_in, const int* in_sizes, int n_in,
                              void* d_out, int out_size, void* d_ws, size_t ws_size,
                              hipStream_t stream) {
  (void)in_sizes; (void)n_in; (void)out_size; (void)ws_size;
  const float* x   = (const float*)d_in[0];
  const float* qW  = (const float*)d_in[1];
  const float* qb  = (const float*)d_in[2];
  const float* qcw = (const float*)d_in[3];
  const float* qcb = (const float*)d_in[4];
  const float* kW  = (const float*)d_in[5];
  const float* kb  = (const float*)d_in[6];
  const float* kcw = (const float*)d_in[7];
  const float* kcb = (const float*)d_in[8];
  const float* vW  = (const float*)d_in[9];
  const float* vb  = (const float*)d_in[10];
  const float* vcw = (const float*)d_in[11];
  const float* vcb = (const float*)d_in[12];
  const float* oW  = (const float*)d_in[13];
  const float* ob  = (const float*)d_in[14];
  const float* er  = (const float*)d_in[15];
  float* out = (float*)d_out;

  const size_t NE = (size_t)B_ * W_ * C_;  // 4M
  const size_t NW = (size_t)C_ * C_;       // 1M
  short* ws   = (short*)d_ws;
  short* xh    = ws;                         // 4M sh (vt reuses after QKV GEMM)
  short* wqkvh = xh + NE;                    // 3M sh
  short* oWh   = wqkvh + 3 * NW;             // 1M sh
  short* ertb  = oWh + NW;                   // 64K sh
  short* yqkv  = ertb + (size_t)W_ * D_;     // 4096*3072 sh (oat reuses)
  short* qc    = yqkv + (size_t)(B_ * W_) * (3 * C_);
  short* kc    = qc + NE;
  short* vc    = kc + NE;
  short* vt    = xh;    // xh dead after QKV GEMM
  short* oat   = yqkv;  // yqkv dead after conv
  // total = 65.7 MB (round-2 proved >= 67.1 MB available)

  cast_bf16_kernel<<<2048, 256, 0, stream>>>(x, xh, (int)(NE / 8));
  cast4_kernel<<<dim3(512, 4), 256, 0, stream>>>(qW, kW, vW, oW, wqkvh, wqkvh + NW,
                                                 wqkvh + 2 * NW, oWh);
  transpose_er_kernel<<<64, 256, 0, stream>>>(er, ertb);

  const int M = B_ * W_;
  dim3 gq(3 * C_ / 128, M / 128);  // (24, 32) fused QKV
  gemm_bf16_v2<0><<<gq, 256, 0, stream>>>(xh, wqkvh, qb, kb, vb, yqkv, M, 3 * C_, C_);

  dwconv3_kernel<<<dim3(2048, 3), 256, 0, stream>>>(yqkv, qcw, qcb, kcw, kcb, vcw, vcb,
                                                    qc, kc, vc);

  transpose_v_kernel<<<dim3(W_ / 64, B_ * H_), 256, 0, stream>>>(vc, vt);

  attn_v2_kernel<<<1024, 256, 0, stream>>>(qc, kc, vt, ertb, oat);

  dim3 go(C_ / 128, M / 128);  // (8, 32)
  gemm_bf16_v2<1><<<go, 256, 0, stream>>>(oat, oWh, ob, ob, ob, out, M, C_, C_);
}

// Round 8
// 258.662 us; speedup vs baseline: 4.6851x; 1.0918x over previous
//
#include <hip/hip_runtime.h>

#define B_ 4
#define W_ 1024
#define C_ 1024
#define H_ 16
#define D_ 64

typedef __attribute__((ext_vector_type(8))) short short8;
typedef __attribute__((ext_vector_type(4))) float f32x4;

__device__ __forceinline__ unsigned short f2b(float f) {
  unsigned u = __builtin_bit_cast(unsigned, f);
  unsigned r = (u + 0x7fffu + ((u >> 16) & 1u)) >> 16;
  return (unsigned short)r;
}
__device__ __forceinline__ float b2f(short b) {
  return __builtin_bit_cast(float, ((unsigned)(unsigned short)b) << 16);
}
// T12 recipe: packed f32x2 -> bf16x2 (dst.lo = bf16(a), dst.hi = bf16(b))
__device__ __forceinline__ unsigned pk2(float a, float b) {
  unsigned r;
  asm("v_cvt_pk_bf16_f32 %0, %1, %2" : "=v"(r) : "v"(a), "v"(b));
  return r;
}

// async global->LDS, 16B per lane. dst must be wave-uniform base + lane*16.
typedef __attribute__((address_space(1))) void GV;
typedef __attribute__((address_space(3))) void LV;
__device__ __forceinline__ void gl16(const short* g, short* l) {
  __builtin_amdgcn_global_load_lds((GV*)g, (LV*)l, 16, 0, 0);
}

// ---------------------------------------------------------------------------
// prep: x cast (blocks 0..2047), 4 weights cast (2048..4095), er transpose
// (4096..4159). Single dispatch replaces 3.
// ---------------------------------------------------------------------------
__global__ __launch_bounds__(256)
void prep_kernel(const float* __restrict__ x, const float* __restrict__ qW,
                 const float* __restrict__ kW, const float* __restrict__ vW,
                 const float* __restrict__ oW, const float* __restrict__ er,
                 short* __restrict__ xh, short* __restrict__ wh,
                 short* __restrict__ ertb) {
  const int bx = blockIdx.x;
  const int tid = threadIdx.x;
  if (bx < 4096) {
    const float* s;
    short* d;
    size_t u;
    if (bx < 2048) {
      u = (size_t)bx * 256 + tid;
      s = x; d = xh;
    } else {
      u = (size_t)(bx - 2048) * 256 + tid;  // 0..524287 over 4 matrices
      const int w = (int)(u >> 17);
      s = (w == 0) ? qW : (w == 1) ? kW : (w == 2) ? vW : oW;
      d = wh + (u & ~(size_t)131071) * 8;   // contiguous wqkv|oW region
      u &= 131071;
      const float4* p = (const float4*)s + u * 2;
      float4 a = p[0], b = p[1];
      short8 r;
      r[0] = f2b(a.x); r[1] = f2b(a.y); r[2] = f2b(a.z); r[3] = f2b(a.w);
      r[4] = f2b(b.x); r[5] = f2b(b.y); r[6] = f2b(b.z); r[7] = f2b(b.w);
      *((short8*)d + u) = r;
      return;
    }
    const float4* p = (const float4*)s + u * 2;
    float4 a = p[0], b = p[1];
    short8 r;
    r[0] = f2b(a.x); r[1] = f2b(a.y); r[2] = f2b(a.z); r[3] = f2b(a.w);
    r[4] = f2b(b.x); r[5] = f2b(b.y); r[6] = f2b(b.z); r[7] = f2b(b.w);
    *((short8*)d + u) = r;
  } else {
    int i = (bx - 4096) * 256 + tid;  // D * W/4 = 16384
    int d = i >> 8;
    int w4 = (i & 255) << 2;
    float4 v = *(const float4*)(er + (size_t)d * W_ + w4);
    ertb[(size_t)(w4 + 0) * D_ + d] = f2b(v.x);
    ertb[(size_t)(w4 + 1) * D_ + d] = f2b(v.y);
    ertb[(size_t)(w4 + 2) * D_ + d] = f2b(v.z);
    ertb[(size_t)(w4 + 3) * D_ + d] = f2b(v.w);
  }
}

// ---------------------------------------------------------------------------
// m97-style MFMA GEMM: out = A(M,K) @ Wt(N,K)^T + bias. 128x128 tile, BK=64,
// global_load_lds(16B) into linear LDS, 2-barrier K-loop.
// ---------------------------------------------------------------------------
template <int OUTF32>
__global__ __launch_bounds__(256)
void gemm_bf16_v2(const short* __restrict__ A, const short* __restrict__ Wt,
                  const float* __restrict__ b0, const float* __restrict__ b1,
                  const float* __restrict__ b2, void* __restrict__ outv,
                  int M, int N, int K) {
  __shared__ short sA[128 * 64];
  __shared__ short sB[128 * 64];
  const int tid = threadIdx.x;
  const int bm = blockIdx.y * 128, bn = blockIdx.x * 128;
  const int wv = tid >> 6, lane = tid & 63;
  const int wr = (wv >> 1) * 64, wc = (wv & 1) * 64;
  const int l15 = lane & 15, l4 = lane >> 4;
  const int srow = tid >> 3;
  const int scs = (tid & 7) * 8;
  const short* ga = A + (size_t)(bm + srow) * K + scs;
  const short* gb = Wt + (size_t)(bn + srow) * K + scs;
  short* la = sA + tid * 8;
  short* lb = sB + tid * 8;

  f32x4 acc[4][4];
#pragma unroll
  for (int mf = 0; mf < 4; ++mf)
#pragma unroll
    for (int nf = 0; nf < 4; ++nf) acc[mf][nf] = (f32x4){0.f, 0.f, 0.f, 0.f};

  for (int k0 = 0; k0 < K; k0 += 64) {
    __syncthreads();
#pragma unroll
    for (int i = 0; i < 4; ++i) {
      gl16(ga + (size_t)(i * 32) * K + k0, la + i * 2048);
      gl16(gb + (size_t)(i * 32) * K + k0, lb + i * 2048);
    }
    __syncthreads();
#pragma unroll
    for (int ks = 0; ks < 2; ++ks) {
      short8 af[4], bf[4];
#pragma unroll
      for (int mf = 0; mf < 4; ++mf)
        af[mf] = *(short8*)(sA + (wr + mf * 16 + l15) * 64 + ks * 32 + l4 * 8);
#pragma unroll
      for (int nf = 0; nf < 4; ++nf)
        bf[nf] = *(short8*)(sB + (wc + nf * 16 + l15) * 64 + ks * 32 + l4 * 8);
#pragma unroll
      for (int mf = 0; mf < 4; ++mf)
#pragma unroll
        for (int nf = 0; nf < 4; ++nf)
          acc[mf][nf] = __builtin_amdgcn_mfma_f32_16x16x32_bf16(af[mf], bf[nf], acc[mf][nf], 0, 0, 0);
    }
  }
#pragma unroll
  for (int mf = 0; mf < 4; ++mf) {
#pragma unroll
    for (int nf = 0; nf < 4; ++nf) {
      const int n = bn + wc + nf * 16 + l15;
      const float bs = (n < 1024) ? b0[n] : ((n < 2048) ? b1[n - 1024] : b2[n - 2048]);
#pragma unroll
      for (int r = 0; r < 4; ++r) {
        const int m = bm + wr + mf * 16 + l4 * 4 + r;
        const float v = acc[mf][nf][r] + bs;
        if (OUTF32) ((float*)outv)[(size_t)m * N + n] = v;
        else        ((short*)outv)[(size_t)m * N + n] = (short)f2b(v);
      }
    }
  }
}

// ---------------------------------------------------------------------------
// Causal depthwise conv K=3 for q,k planes of yqkv (B*W, 3C); y selects plane
// ---------------------------------------------------------------------------
__global__ __launch_bounds__(256)
void dwconv_qk_kernel(const short* __restrict__ yqkv,
                      const float* __restrict__ qcw, const float* __restrict__ qcb,
                      const float* __restrict__ kcw, const float* __restrict__ kcb,
                      short* __restrict__ qc, short* __restrict__ kc) {
  const int t = blockIdx.y;
  const float* cw = t ? kcw : qcw;
  const float* cb = t ? kcb : qcb;
  short* out = t ? kc : qc;
  const int idx = blockIdx.x * 256 + threadIdx.x;  // over B*W*(C/8)
  const int c8 = (idx & (C_ / 8 - 1)) << 3;
  const int bw = idx >> 7;
  const int w = bw & (W_ - 1);
  const short* base = yqkv + (size_t)bw * (3 * C_) + t * C_ + c8;
  short8 x2 = *(const short8*)base;
  short8 x1, x0;
  if (w >= 1) x1 = *(const short8*)(base - 3 * C_); else { for (int j = 0; j < 8; ++j) x1[j] = 0; }
  if (w >= 2) x0 = *(const short8*)(base - 6 * C_); else { for (int j = 0; j < 8; ++j) x0[j] = 0; }
  short8 r;
#pragma unroll
  for (int j = 0; j < 8; ++j) {
    const int c = c8 + j;
    float acc = b2f(x0[j]) * cw[c * 3 + 0] + b2f(x1[j]) * cw[c * 3 + 1] +
                b2f(x2[j]) * cw[c * 3 + 2] + cb[c];
    r[j] = (short)f2b(acc);
  }
  *(short8*)(out + (size_t)bw * C_ + c8) = r;
}

// ---------------------------------------------------------------------------
// V plane: causal dwconv fused with head-transpose. yqkv plane 2 -> vt(B*H,D,W)
// ---------------------------------------------------------------------------
__global__ __launch_bounds__(256)
void dwconv_vt_kernel(const short* __restrict__ yqkv, const float* __restrict__ vcw,
                      const float* __restrict__ vcb, short* __restrict__ vt) {
  __shared__ short t[64][72];
  const int bh = blockIdx.y, w0 = blockIdx.x * 64;
  const int b = bh >> 4, h = bh & 15;
  const int tid = threadIdx.x;
  for (int c = tid; c < 512; c += 256) {
    const int w = c >> 3, dg = c & 7;
    const int gw = w0 + w;
    const short* base = yqkv + ((size_t)(b * W_ + gw)) * (3 * C_) + 2 * C_ + h * 64 + dg * 8;
    short8 x2 = *(const short8*)base;
    short8 x1, x0;
    if (gw >= 1) x1 = *(const short8*)(base - 3 * C_); else { for (int j = 0; j < 8; ++j) x1[j] = 0; }
    if (gw >= 2) x0 = *(const short8*)(base - 6 * C_); else { for (int j = 0; j < 8; ++j) x0[j] = 0; }
#pragma unroll
    for (int j = 0; j < 8; ++j) {
      const int ch = h * 64 + dg * 8 + j;
      float acc = b2f(x0[j]) * vcw[ch * 3 + 0] + b2f(x1[j]) * vcw[ch * 3 + 1] +
                  b2f(x2[j]) * vcw[ch * 3 + 2] + vcb[ch];
      t[dg * 8 + j][w] = (short)f2b(acc);
    }
  }
  __syncthreads();
  for (int c = tid; c < 512; c += 256) {
    const int d = c >> 3, wg = c & 7;
    *(short8*)(vt + ((size_t)(bh * 64 + d)) * W_ + w0 + wg * 8) = *(short8*)&t[d][wg * 8];
  }
}

// ---------------------------------------------------------------------------
// Fused skewed attention, swapped-S, T2 both-sides XOR swizzle (rule #21):
// LDS dest linear (global_load_lds), global SOURCE chunk-permuted, reads
// XOR-swizzled. A-frag reads now 2-way (free) instead of 16-way.
// ---------------------------------------------------------------------------
__global__ __launch_bounds__(256)
void attn_v3_kernel(const short* __restrict__ q, const short* __restrict__ k,
                    const short* __restrict__ vt, const short* __restrict__ ert,
                    short* __restrict__ o) {
  __shared__ short sK[2][4096];
  __shared__ short sQj[2][4096];
  __shared__ short sVt[2][4096];
  __shared__ short sU[8192];  // {sQ | sE} then sP (pitch 64, swizzled)
  short* sQ = sU;
  short* sE = sU + 4096;
  short* sP = sU;

  const int tid = threadIdx.x;
  const int wid = blockIdx.x;
  const int swz = (wid & 7) * 128 + (wid >> 3);  // T1: XCD gets contiguous bh
  const int bh = swz >> 4, qt = swz & 15;
  const int b = bh >> 4, h = bh & 15;
  const int i0 = qt * 64;
  const int wv = tid >> 6, lane = tid & 63;
  const int l15 = lane & 15, l4 = lane >> 4;
  const size_t bW = (size_t)b * W_;
  const int srow = tid >> 3;
  const int swsc = ((tid & 7) ^ (srow & 7)) * 8;  // inverse-swizzled source chunk
  const int cxor = (l15 & 7) * 8;                 // read-side XOR (shorts)

  const short* qbase = q + bW * C_ + h * 64;
  const short* kbase = k + bW * C_ + h * 64;
  const short* vbase = vt + (size_t)bh * 64 * W_;

  {
    const short* g;
    g = qbase + (size_t)(i0 + srow) * C_ + swsc;
    gl16(g, sQ + tid * 8); gl16(g + (size_t)32 * C_, sQ + 2048 + tid * 8);
    g = ert + (size_t)(i0 + srow) * 64 + swsc;
    gl16(g, sE + tid * 8); gl16(g + 32 * 64, sE + 2048 + tid * 8);
    g = kbase + (size_t)srow * C_ + swsc;
    gl16(g, sK[0] + tid * 8); gl16(g + (size_t)32 * C_, sK[0] + 2048 + tid * 8);
    g = qbase + (size_t)srow * C_ + swsc;
    gl16(g, sQj[0] + tid * 8); gl16(g + (size_t)32 * C_, sQj[0] + 2048 + tid * 8);
    g = vbase + (size_t)srow * W_ + swsc;
    gl16(g, sVt[0] + tid * 8); gl16(g + (size_t)32 * W_, sVt[0] + 2048 + tid * 8);
  }
  __syncthreads();

  short8 bQ[2], bE[2];
#pragma unroll
  for (int ks = 0; ks < 2; ++ks) {
    const int off = (ks * 32 + l4 * 8) ^ cxor;
    bQ[ks] = *(short8*)(sQ + (wv * 16 + l15) * 64 + off);
    bE[ks] = *(short8*)(sE + (wv * 16 + l15) * 64 + off);
  }
  __syncthreads();  // all waves done with sQ/sE before sP overwrites union

  float m_ = -1e30f, l_ = 0.f;
  f32x4 accO[4];
#pragma unroll
  for (int mf = 0; mf < 4; ++mf) accO[mf] = (f32x4){0.f, 0.f, 0.f, 0.f};
  const float SC = 0.03125f;  // 1/sqrt(C)

  for (int jt = 0; jt < 16; ++jt) {
    const int cur = jt & 1;
    if (jt < 15) {
      const int j0n = (jt + 1) * 64;
      const short* g;
      g = kbase + (size_t)(j0n + srow) * C_ + swsc;
      gl16(g, sK[cur ^ 1] + tid * 8); gl16(g + (size_t)32 * C_, sK[cur ^ 1] + 2048 + tid * 8);
      g = qbase + (size_t)(j0n + srow) * C_ + swsc;
      gl16(g, sQj[cur ^ 1] + tid * 8); gl16(g + (size_t)32 * C_, sQj[cur ^ 1] + 2048 + tid * 8);
      g = vbase + (size_t)srow * W_ + j0n + swsc;
      gl16(g, sVt[cur ^ 1] + tid * 8); gl16(g + (size_t)32 * W_, sVt[cur ^ 1] + 2048 + tid * 8);
    }

    f32x4 s[4];
#pragma unroll
    for (int mf = 0; mf < 4; ++mf) s[mf] = (f32x4){0.f, 0.f, 0.f, 0.f};
    const int ofA = (l4 * 8) ^ cxor;
    const int ofB = (32 + l4 * 8) ^ cxor;
    __builtin_amdgcn_s_setprio(1);
#pragma unroll
    for (int mf = 0; mf < 4; ++mf) {
      const short* kp = sK[cur] + (mf * 16 + l15) * 64;
      const short* jp = sQj[cur] + (mf * 16 + l15) * 64;
      s[mf] = __builtin_amdgcn_mfma_f32_16x16x32_bf16(*(short8*)(kp + ofA), bQ[0], s[mf], 0, 0, 0);
      s[mf] = __builtin_amdgcn_mfma_f32_16x16x32_bf16(*(short8*)(kp + ofB), bQ[1], s[mf], 0, 0, 0);
      s[mf] = __builtin_amdgcn_mfma_f32_16x16x32_bf16(*(short8*)(jp + ofA), bE[0], s[mf], 0, 0, 0);
      s[mf] = __builtin_amdgcn_mfma_f32_16x16x32_bf16(*(short8*)(jp + ofB), bE[1], s[mf], 0, 0, 0);
    }
    __builtin_amdgcn_s_setprio(0);

    float px = fmaxf(fmaxf(s[0][0], s[0][1]), fmaxf(s[0][2], s[0][3]));
#pragma unroll
    for (int mf = 1; mf < 4; ++mf)
      px = fmaxf(px, fmaxf(fmaxf(s[mf][0], s[mf][1]), fmaxf(s[mf][2], s[mf][3])));
    px = fmaxf(px, __shfl_xor(px, 16));
    px = fmaxf(px, __shfl_xor(px, 32));
    px *= SC;
    if (!__all(px <= m_ + 8.f)) {  // T13 defer-max
      const float mn = fmaxf(m_, px);
      const float sc = __expf(m_ - mn);
      l_ *= sc;
#pragma unroll
      for (int mf = 0; mf < 4; ++mf)
#pragma unroll
        for (int r = 0; r < 4; ++r) accO[mf][r] *= sc;
      m_ = mn;
    }
    float p[4][4];
    float rs = 0.f;
#pragma unroll
    for (int mf = 0; mf < 4; ++mf)
#pragma unroll
      for (int r = 0; r < 4; ++r) {
        p[mf][r] = __expf(__builtin_fmaf(s[mf][r], SC, -m_));
        rs += p[mf][r];
      }
    rs += __shfl_xor(rs, 16);
    rs += __shfl_xor(rs, 32);
    l_ += rs;

    // sP swizzled write: logical chunk (2mf + l4/2), sub-half (l4&1)
#pragma unroll
    for (int mf = 0; mf < 4; ++mf) {
      uint2 w2;
      w2.x = pk2(p[mf][0], p[mf][1]);
      w2.y = pk2(p[mf][2], p[mf][3]);
      const int off = (((2 * mf + (l4 >> 1)) ^ (l15 & 7)) * 8) + (l4 & 1) * 4;
      *(uint2*)(sP + (wv * 16 + l15) * 64 + off) = w2;
    }

    short8 pf[2];
#pragma unroll
    for (int ks = 0; ks < 2; ++ks)
      pf[ks] = *(short8*)(sP + (wv * 16 + l15) * 64 + ((ks * 32 + l4 * 8) ^ cxor));
    __builtin_amdgcn_s_setprio(1);
#pragma unroll
    for (int mf = 0; mf < 4; ++mf) {
      const short* vp = sVt[cur] + (mf * 16 + l15) * 64;
      accO[mf] = __builtin_amdgcn_mfma_f32_16x16x32_bf16(*(short8*)(vp + ofA), pf[0], accO[mf], 0, 0, 0);
      accO[mf] = __builtin_amdgcn_mfma_f32_16x16x32_bf16(*(short8*)(vp + ofB), pf[1], accO[mf], 0, 0, 0);
    }
    __builtin_amdgcn_s_setprio(0);

    __syncthreads();
  }

  const float inv = 1.f / l_;
  const size_t orow = (bW + i0 + wv * 16 + l15) * C_ + h * 64;
#pragma unroll
  for (int mf = 0; mf < 4; ++mf) {
    uint2 w2;
    w2.x = pk2(accO[mf][0] * inv, accO[mf][1] * inv);
    w2.y = pk2(accO[mf][2] * inv, accO[mf][3] * inv);
    *(uint2*)(o + orow + mf * 16 + l4 * 4) = w2;
  }
}

// ---------------------------------------------------------------------------
extern "C" void kernel_launch(void* const* d_in, const int* in_sizes, int n_in,
                              void* d_out, int out_size, void* d_ws, size_t ws_size,
                              hipStream_t stream) {
  (void)in_sizes; (void)n_in; (void)out_size; (void)ws_size;
  const float* x   = (const float*)d_in[0];
  const float* qW  = (const float*)d_in[1];
  const float* qb  = (const float*)d_in[2];
  const float* qcw = (const float*)d_in[3];
  const float* qcb = (const float*)d_in[4];
  const float* kW  = (const float*)d_in[5];
  const float* kb  = (const float*)d_in[6];
  const float* kcw = (const float*)d_in[7];
  const float* kcb = (const float*)d_in[8];
  const float* vW  = (const float*)d_in[9];
  const float* vb  = (const float*)d_in[10];
  const float* vcw = (const float*)d_in[11];
  const float* vcb = (const float*)d_in[12];
  const float* oW  = (const float*)d_in[13];
  const float* ob  = (const float*)d_in[14];
  const float* er  = (const float*)d_in[15];
  float* out = (float*)d_out;

  const size_t NE = (size_t)B_ * W_ * C_;  // 4M
  const size_t NW = (size_t)C_ * C_;       // 1M
  short* ws   = (short*)d_ws;
  short* xh    = ws;                        // 4M sh; dead after QKV GEMM -> vt
  short* wqkvh = xh + NE;                   // 3M sh (+oWh contiguous)
  short* oWh   = wqkvh + 3 * NW;            // 1M sh
  short* ertb  = oWh + NW;                  // 64K sh
  short* yqkv  = ertb + (size_t)W_ * D_;    // 12M sh; dead after convs -> oat
  short* qc    = yqkv + (size_t)(B_ * W_) * (3 * C_);
  short* kc    = qc + NE;
  short* vt    = xh;
  short* oat   = yqkv;
  // total = 56.1 MB (< 65.7 MB proven in round 4)

  prep_kernel<<<4160, 256, 0, stream>>>(x, qW, kW, vW, oW, er, xh, wqkvh, ertb);

  const int M = B_ * W_;
  dim3 gq(3 * C_ / 128, M / 128);  // (24, 32) fused QKV
  gemm_bf16_v2<0><<<gq, 256, 0, stream>>>(xh, wqkvh, qb, kb, vb, yqkv, M, 3 * C_, C_);

  dwconv_qk_kernel<<<dim3(2048, 2), 256, 0, stream>>>(yqkv, qcw, qcb, kcw, kcb, qc, kc);
  dwconv_vt_kernel<<<dim3(W_ / 64, B_ * H_), 256, 0, stream>>>(yqkv, vcw, vcb, vt);

  attn_v3_kernel<<<1024, 256, 0, stream>>>(qc, kc, vt, ertb, oat);

  dim3 go(C_ / 128, M / 128);  // (8, 32)
  gemm_bf16_v2<1><<<go, 256, 0, stream>>>(oat, oWh, ob, ob, ob, out, M, C_, C_);
}

// Round 9
// 242.302 us; speedup vs baseline: 5.0014x; 1.0675x over previous
//
#include <hip/hip_runtime.h>

#define B_ 4
#define W_ 1024
#define C_ 1024
#define H_ 16
#define D_ 64

typedef __attribute__((ext_vector_type(8))) short short8;
typedef __attribute__((ext_vector_type(4))) float f32x4;

__device__ __forceinline__ unsigned short f2b(float f) {
  unsigned u = __builtin_bit_cast(unsigned, f);
  unsigned r = (u + 0x7fffu + ((u >> 16) & 1u)) >> 16;
  return (unsigned short)r;
}
__device__ __forceinline__ float b2f(short b) {
  return __builtin_bit_cast(float, ((unsigned)(unsigned short)b) << 16);
}
// T12 recipe: packed f32x2 -> bf16x2 (dst.lo = bf16(a), dst.hi = bf16(b))
__device__ __forceinline__ unsigned pk2(float a, float b) {
  unsigned r;
  asm("v_cvt_pk_bf16_f32 %0, %1, %2" : "=v"(r) : "v"(a), "v"(b));
  return r;
}

// async global->LDS, 16B per lane. dst must be wave-uniform base + lane*16.
typedef __attribute__((address_space(1))) void GV;
typedef __attribute__((address_space(3))) void LV;
__device__ __forceinline__ void gl16(const short* g, short* l) {
  __builtin_amdgcn_global_load_lds((GV*)g, (LV*)l, 16, 0, 0);
}

// ---------------------------------------------------------------------------
// prep: x cast (blocks 0..2047), 4 weights cast (2048..4095), er transpose
// (4096..4159). Single dispatch replaces 3.
// ---------------------------------------------------------------------------
__global__ __launch_bounds__(256)
void prep_kernel(const float* __restrict__ x, const float* __restrict__ qW,
                 const float* __restrict__ kW, const float* __restrict__ vW,
                 const float* __restrict__ oW, const float* __restrict__ er,
                 short* __restrict__ xh, short* __restrict__ wh,
                 short* __restrict__ ertb) {
  const int bx = blockIdx.x;
  const int tid = threadIdx.x;
  if (bx < 4096) {
    const float* s;
    short* d;
    size_t u;
    if (bx < 2048) {
      u = (size_t)bx * 256 + tid;
      s = x; d = xh;
    } else {
      u = (size_t)(bx - 2048) * 256 + tid;  // 0..524287 over 4 matrices
      const int w = (int)(u >> 17);
      s = (w == 0) ? qW : (w == 1) ? kW : (w == 2) ? vW : oW;
      d = wh + (u & ~(size_t)131071) * 8;   // contiguous wqkv|oW region
      u &= 131071;
      const float4* p = (const float4*)s + u * 2;
      float4 a = p[0], b = p[1];
      short8 r;
      r[0] = f2b(a.x); r[1] = f2b(a.y); r[2] = f2b(a.z); r[3] = f2b(a.w);
      r[4] = f2b(b.x); r[5] = f2b(b.y); r[6] = f2b(b.z); r[7] = f2b(b.w);
      *((short8*)d + u) = r;
      return;
    }
    const float4* p = (const float4*)s + u * 2;
    float4 a = p[0], b = p[1];
    short8 r;
    r[0] = f2b(a.x); r[1] = f2b(a.y); r[2] = f2b(a.z); r[3] = f2b(a.w);
    r[4] = f2b(b.x); r[5] = f2b(b.y); r[6] = f2b(b.z); r[7] = f2b(b.w);
    *((short8*)d + u) = r;
  } else {
    int i = (bx - 4096) * 256 + tid;  // D * W/4 = 16384
    int d = i >> 8;
    int w4 = (i & 255) << 2;
    float4 v = *(const float4*)(er + (size_t)d * W_ + w4);
    ertb[(size_t)(w4 + 0) * D_ + d] = f2b(v.x);
    ertb[(size_t)(w4 + 1) * D_ + d] = f2b(v.y);
    ertb[(size_t)(w4 + 2) * D_ + d] = f2b(v.z);
    ertb[(size_t)(w4 + 3) * D_ + d] = f2b(v.w);
  }
}

// ---------------------------------------------------------------------------
// GEMM v3: 128x128 tile, BK=64, 2-phase dbuf via counted vmcnt (T3/T4-min),
// T2 both-sides XOR swizzle (inverse-swizzled gl16 source + XOR'd ds_read).
// Raw s_barrier (no vmcnt(0) drain) keeps next tile's loads in flight.
// ---------------------------------------------------------------------------
#define GSTAGE(T, BUF)                                                       \
  {                                                                          \
    const int k0_ = (T) * 64;                                                \
    gl16(ga + (size_t)0  * K + k0_, sA[BUF] + 0    + ldst);                  \
    gl16(gb + (size_t)0  * K + k0_, sB[BUF] + 0    + ldst);                  \
    gl16(ga + (size_t)32 * K + k0_, sA[BUF] + 2048 + ldst);                  \
    gl16(gb + (size_t)32 * K + k0_, sB[BUF] + 2048 + ldst);                  \
    gl16(ga + (size_t)64 * K + k0_, sA[BUF] + 4096 + ldst);                  \
    gl16(gb + (size_t)64 * K + k0_, sB[BUF] + 4096 + ldst);                  \
    gl16(ga + (size_t)96 * K + k0_, sA[BUF] + 6144 + ldst);                  \
    gl16(gb + (size_t)96 * K + k0_, sB[BUF] + 6144 + ldst);                  \
  }

template <int OUTF32>
__global__ __launch_bounds__(256)
void gemm_bf16_v3(const short* __restrict__ A, const short* __restrict__ Wt,
                  const float* __restrict__ b0, const float* __restrict__ b1,
                  const float* __restrict__ b2, void* __restrict__ outv,
                  int M, int N, int K) {
  __shared__ short sA[2][128 * 64];
  __shared__ short sB[2][128 * 64];
  const int tid = threadIdx.x;
  const int bm = blockIdx.y * 128, bn = blockIdx.x * 128;
  const int wv = tid >> 6, lane = tid & 63;
  const int wr = (wv >> 1) * 64, wc = (wv & 1) * 64;
  const int l15 = lane & 15, l4 = lane >> 4;
  const int srow = tid >> 3;                      // staged row 0..31 (of each 32-row group)
  const int swsc = ((tid & 7) ^ (srow & 7)) * 8;  // inverse-swizzled source chunk
  const int cxor = (l15 & 7) * 8;                 // read-side XOR
  const int ldst = tid * 8;                       // linear LDS dest (gl16 requirement)
  const short* ga = A + (size_t)(bm + srow) * K + swsc;
  const short* gb = Wt + (size_t)(bn + srow) * K + swsc;

  f32x4 acc[4][4];
#pragma unroll
  for (int mf = 0; mf < 4; ++mf)
#pragma unroll
    for (int nf = 0; nf < 4; ++nf) acc[mf][nf] = (f32x4){0.f, 0.f, 0.f, 0.f};

  const int nt = K >> 6;
  GSTAGE(0, 0)
  for (int t = 0; t < nt; ++t) {
    const int cur = t & 1;
    if (t + 1 < nt) {
      GSTAGE(t + 1, cur ^ 1)
      asm volatile("s_waitcnt vmcnt(8)" ::: "memory");  // tile t landed; t+1 in flight
    } else {
      asm volatile("s_waitcnt vmcnt(0)" ::: "memory");
    }
    __builtin_amdgcn_s_barrier();
    __builtin_amdgcn_sched_barrier(0);
#pragma unroll
    for (int ks = 0; ks < 2; ++ks) {
      short8 af[4], bf[4];
#pragma unroll
      for (int mf = 0; mf < 4; ++mf)
        af[mf] = *(short8*)(sA[cur] + (wr + mf * 16 + l15) * 64 + ((ks * 32 + l4 * 8) ^ cxor));
#pragma unroll
      for (int nf = 0; nf < 4; ++nf)
        bf[nf] = *(short8*)(sB[cur] + (wc + nf * 16 + l15) * 64 + ((ks * 32 + l4 * 8) ^ cxor));
#pragma unroll
      for (int mf = 0; mf < 4; ++mf)
#pragma unroll
        for (int nf = 0; nf < 4; ++nf)
          acc[mf][nf] = __builtin_amdgcn_mfma_f32_16x16x32_bf16(af[mf], bf[nf], acc[mf][nf], 0, 0, 0);
    }
    __builtin_amdgcn_sched_barrier(0);
    __builtin_amdgcn_s_barrier();  // all waves done reading buf[cur] before t+1 stages into it
  }
#pragma unroll
  for (int mf = 0; mf < 4; ++mf) {
#pragma unroll
    for (int nf = 0; nf < 4; ++nf) {
      const int n = bn + wc + nf * 16 + l15;
      const float bs = (n < 1024) ? b0[n] : ((n < 2048) ? b1[n - 1024] : b2[n - 2048]);
#pragma unroll
      for (int r = 0; r < 4; ++r) {
        const int m = bm + wr + mf * 16 + l4 * 4 + r;
        const float v = acc[mf][nf][r] + bs;
        if (OUTF32) ((float*)outv)[(size_t)m * N + n] = v;
        else        ((short*)outv)[(size_t)m * N + n] = (short)f2b(v);
      }
    }
  }
}

// ---------------------------------------------------------------------------
// Causal depthwise conv K=3 for q,k planes of yqkv (B*W, 3C); y selects plane
// ---------------------------------------------------------------------------
__global__ __launch_bounds__(256)
void dwconv_qk_kernel(const short* __restrict__ yqkv,
                      const float* __restrict__ qcw, const float* __restrict__ qcb,
                      const float* __restrict__ kcw, const float* __restrict__ kcb,
                      short* __restrict__ qc, short* __restrict__ kc) {
  const int t = blockIdx.y;
  const float* cw = t ? kcw : qcw;
  const float* cb = t ? kcb : qcb;
  short* out = t ? kc : qc;
  const int idx = blockIdx.x * 256 + threadIdx.x;  // over B*W*(C/8)
  const int c8 = (idx & (C_ / 8 - 1)) << 3;
  const int bw = idx >> 7;
  const int w = bw & (W_ - 1);
  const short* base = yqkv + (size_t)bw * (3 * C_) + t * C_ + c8;
  short8 x2 = *(const short8*)base;
  short8 x1, x0;
  if (w >= 1) x1 = *(const short8*)(base - 3 * C_); else { for (int j = 0; j < 8; ++j) x1[j] = 0; }
  if (w >= 2) x0 = *(const short8*)(base - 6 * C_); else { for (int j = 0; j < 8; ++j) x0[j] = 0; }
  short8 r;
#pragma unroll
  for (int j = 0; j < 8; ++j) {
    const int c = c8 + j;
    float acc = b2f(x0[j]) * cw[c * 3 + 0] + b2f(x1[j]) * cw[c * 3 + 1] +
                b2f(x2[j]) * cw[c * 3 + 2] + cb[c];
    r[j] = (short)f2b(acc);
  }
  *(short8*)(out + (size_t)bw * C_ + c8) = r;
}

// ---------------------------------------------------------------------------
// V plane: causal dwconv fused with head-transpose. yqkv plane 2 -> vt(B*H,D,W)
// ---------------------------------------------------------------------------
__global__ __launch_bounds__(256)
void dwconv_vt_kernel(const short* __restrict__ yqkv, const float* __restrict__ vcw,
                      const float* __restrict__ vcb, short* __restrict__ vt) {
  __shared__ short t[64][72];
  const int bh = blockIdx.y, w0 = blockIdx.x * 64;
  const int b = bh >> 4, h = bh & 15;
  const int tid = threadIdx.x;
  for (int c = tid; c < 512; c += 256) {
    const int w = c >> 3, dg = c & 7;
    const int gw = w0 + w;
    const short* base = yqkv + ((size_t)(b * W_ + gw)) * (3 * C_) + 2 * C_ + h * 64 + dg * 8;
    short8 x2 = *(const short8*)base;
    short8 x1, x0;
    if (gw >= 1) x1 = *(const short8*)(base - 3 * C_); else { for (int j = 0; j < 8; ++j) x1[j] = 0; }
    if (gw >= 2) x0 = *(const short8*)(base - 6 * C_); else { for (int j = 0; j < 8; ++j) x0[j] = 0; }
#pragma unroll
    for (int j = 0; j < 8; ++j) {
      const int ch = h * 64 + dg * 8 + j;
      float acc = b2f(x0[j]) * vcw[ch * 3 + 0] + b2f(x1[j]) * vcw[ch * 3 + 1] +
                  b2f(x2[j]) * vcw[ch * 3 + 2] + vcb[ch];
      t[dg * 8 + j][w] = (short)f2b(acc);
    }
  }
  __syncthreads();
  for (int c = tid; c < 512; c += 256) {
    const int d = c >> 3, wg = c & 7;
    *(short8*)(vt + ((size_t)(bh * 64 + d)) * W_ + w0 + wg * 8) = *(short8*)&t[d][wg * 8];
  }
}

// ---------------------------------------------------------------------------
// Fused skewed attention, swapped-S, T2 both-sides XOR swizzle (rule #21):
// LDS dest linear (global_load_lds), global SOURCE chunk-permuted, reads
// XOR-swizzled. A-frag reads now 2-way (free) instead of 16-way.
// ---------------------------------------------------------------------------
__global__ __launch_bounds__(256)
void attn_v3_kernel(const short* __restrict__ q, const short* __restrict__ k,
                    const short* __restrict__ vt, const short* __restrict__ ert,
                    short* __restrict__ o) {
  __shared__ short sK[2][4096];
  __shared__ short sQj[2][4096];
  __shared__ short sVt[2][4096];
  __shared__ short sU[8192];  // {sQ | sE} then sP (pitch 64, swizzled)
  short* sQ = sU;
  short* sE = sU + 4096;
  short* sP = sU;

  const int tid = threadIdx.x;
  const int wid = blockIdx.x;
  const int swz = (wid & 7) * 128 + (wid >> 3);  // T1: XCD gets contiguous bh
  const int bh = swz >> 4, qt = swz & 15;
  const int b = bh >> 4, h = bh & 15;
  const int i0 = qt * 64;
  const int wv = tid >> 6, lane = tid & 63;
  const int l15 = lane & 15, l4 = lane >> 4;
  const size_t bW = (size_t)b * W_;
  const int srow = tid >> 3;
  const int swsc = ((tid & 7) ^ (srow & 7)) * 8;  // inverse-swizzled source chunk
  const int cxor = (l15 & 7) * 8;                 // read-side XOR (shorts)

  const short* qbase = q + bW * C_ + h * 64;
  const short* kbase = k + bW * C_ + h * 64;
  const short* vbase = vt + (size_t)bh * 64 * W_;

  {
    const short* g;
    g = qbase + (size_t)(i0 + srow) * C_ + swsc;
    gl16(g, sQ + tid * 8); gl16(g + (size_t)32 * C_, sQ + 2048 + tid * 8);
    g = ert + (size_t)(i0 + srow) * 64 + swsc;
    gl16(g, sE + tid * 8); gl16(g + 32 * 64, sE + 2048 + tid * 8);
    g = kbase + (size_t)srow * C_ + swsc;
    gl16(g, sK[0] + tid * 8); gl16(g + (size_t)32 * C_, sK[0] + 2048 + tid * 8);
    g = qbase + (size_t)srow * C_ + swsc;
    gl16(g, sQj[0] + tid * 8); gl16(g + (size_t)32 * C_, sQj[0] + 2048 + tid * 8);
    g = vbase + (size_t)srow * W_ + swsc;
    gl16(g, sVt[0] + tid * 8); gl16(g + (size_t)32 * W_, sVt[0] + 2048 + tid * 8);
  }
  __syncthreads();

  short8 bQ[2], bE[2];
#pragma unroll
  for (int ks = 0; ks < 2; ++ks) {
    const int off = (ks * 32 + l4 * 8) ^ cxor;
    bQ[ks] = *(short8*)(sQ + (wv * 16 + l15) * 64 + off);
    bE[ks] = *(short8*)(sE + (wv * 16 + l15) * 64 + off);
  }
  __syncthreads();  // all waves done with sQ/sE before sP overwrites union

  float m_ = -1e30f, l_ = 0.f;
  f32x4 accO[4];
#pragma unroll
  for (int mf = 0; mf < 4; ++mf) accO[mf] = (f32x4){0.f, 0.f, 0.f, 0.f};
  const float SC = 0.03125f;  // 1/sqrt(C)

  for (int jt = 0; jt < 16; ++jt) {
    const int cur = jt & 1;
    if (jt < 15) {
      const int j0n = (jt + 1) * 64;
      const short* g;
      g = kbase + (size_t)(j0n + srow) * C_ + swsc;
      gl16(g, sK[cur ^ 1] + tid * 8); gl16(g + (size_t)32 * C_, sK[cur ^ 1] + 2048 + tid * 8);
      g = qbase + (size_t)(j0n + srow) * C_ + swsc;
      gl16(g, sQj[cur ^ 1] + tid * 8); gl16(g + (size_t)32 * C_, sQj[cur ^ 1] + 2048 + tid * 8);
      g = vbase + (size_t)srow * W_ + j0n + swsc;
      gl16(g, sVt[cur ^ 1] + tid * 8); gl16(g + (size_t)32 * W_, sVt[cur ^ 1] + 2048 + tid * 8);
    }

    f32x4 s[4];
#pragma unroll
    for (int mf = 0; mf < 4; ++mf) s[mf] = (f32x4){0.f, 0.f, 0.f, 0.f};
    const int ofA = (l4 * 8) ^ cxor;
    const int ofB = (32 + l4 * 8) ^ cxor;
    __builtin_amdgcn_s_setprio(1);
#pragma unroll
    for (int mf = 0; mf < 4; ++mf) {
      const short* kp = sK[cur] + (mf * 16 + l15) * 64;
      const short* jp = sQj[cur] + (mf * 16 + l15) * 64;
      s[mf] = __builtin_amdgcn_mfma_f32_16x16x32_bf16(*(short8*)(kp + ofA), bQ[0], s[mf], 0, 0, 0);
      s[mf] = __builtin_amdgcn_mfma_f32_16x16x32_bf16(*(short8*)(kp + ofB), bQ[1], s[mf], 0, 0, 0);
      s[mf] = __builtin_amdgcn_mfma_f32_16x16x32_bf16(*(short8*)(jp + ofA), bE[0], s[mf], 0, 0, 0);
      s[mf] = __builtin_amdgcn_mfma_f32_16x16x32_bf16(*(short8*)(jp + ofB), bE[1], s[mf], 0, 0, 0);
    }
    __builtin_amdgcn_s_setprio(0);

    float px = fmaxf(fmaxf(s[0][0], s[0][1]), fmaxf(s[0][2], s[0][3]));
#pragma unroll
    for (int mf = 1; mf < 4; ++mf)
      px = fmaxf(px, fmaxf(fmaxf(s[mf][0], s[mf][1]), fmaxf(s[mf][2], s[mf][3])));
    px = fmaxf(px, __shfl_xor(px, 16));
    px = fmaxf(px, __shfl_xor(px, 32));
    px *= SC;
    if (!__all(px <= m_ + 8.f)) {  // T13 defer-max
      const float mn = fmaxf(m_, px);
      const float sc = __expf(m_ - mn);
      l_ *= sc;
#pragma unroll
      for (int mf = 0; mf < 4; ++mf)
#pragma unroll
        for (int r = 0; r < 4; ++r) accO[mf][r] *= sc;
      m_ = mn;
    }
    float p[4][4];
    float rs = 0.f;
#pragma unroll
    for (int mf = 0; mf < 4; ++mf)
#pragma unroll
      for (int r = 0; r < 4; ++r) {
        p[mf][r] = __expf(__builtin_fmaf(s[mf][r], SC, -m_));
        rs += p[mf][r];
      }
    rs += __shfl_xor(rs, 16);
    rs += __shfl_xor(rs, 32);
    l_ += rs;

    // sP swizzled write: logical chunk (2mf + l4/2), sub-half (l4&1)
#pragma unroll
    for (int mf = 0; mf < 4; ++mf) {
      uint2 w2;
      w2.x = pk2(p[mf][0], p[mf][1]);
      w2.y = pk2(p[mf][2], p[mf][3]);
      const int off = (((2 * mf + (l4 >> 1)) ^ (l15 & 7)) * 8) + (l4 & 1) * 4;
      *(uint2*)(sP + (wv * 16 + l15) * 64 + off) = w2;
    }

    short8 pf[2];
#pragma unroll
    for (int ks = 0; ks < 2; ++ks)
      pf[ks] = *(short8*)(sP + (wv * 16 + l15) * 64 + ((ks * 32 + l4 * 8) ^ cxor));
    __builtin_amdgcn_s_setprio(1);
#pragma unroll
    for (int mf = 0; mf < 4; ++mf) {
      const short* vp = sVt[cur] + (mf * 16 + l15) * 64;
      accO[mf] = __builtin_amdgcn_mfma_f32_16x16x32_bf16(*(short8*)(vp + ofA), pf[0], accO[mf], 0, 0, 0);
      accO[mf] = __builtin_amdgcn_mfma_f32_16x16x32_bf16(*(short8*)(vp + ofB), pf[1], accO[mf], 0, 0, 0);
    }
    __builtin_amdgcn_s_setprio(0);

    __syncthreads();
  }

  const float inv = 1.f / l_;
  const size_t orow = (bW + i0 + wv * 16 + l15) * C_ + h * 64;
#pragma unroll
  for (int mf = 0; mf < 4; ++mf) {
    uint2 w2;
    w2.x = pk2(accO[mf][0] * inv, accO[mf][1] * inv);
    w2.y = pk2(accO[mf][2] * inv, accO[mf][3] * inv);
    *(uint2*)(o + orow + mf * 16 + l4 * 4) = w2;
  }
}

// ---------------------------------------------------------------------------
extern "C" void kernel_launch(void* const* d_in, const int* in_sizes, int n_in,
                              void* d_out, int out_size, void* d_ws, size_t ws_size,
                              hipStream_t stream) {
  (void)in_sizes; (void)n_in; (void)out_size; (void)ws_size;
  const float* x   = (const float*)d_in[0];
  const float* qW  = (const float*)d_in[1];
  const float* qb  = (const float*)d_in[2];
  const float* qcw = (const float*)d_in[3];
  const float* qcb = (const float*)d_in[4];
  const float* kW  = (const float*)d_in[5];
  const float* kb  = (const float*)d_in[6];
  const float* kcw = (const float*)d_in[7];
  const float* kcb = (const float*)d_in[8];
  const float* vW  = (const float*)d_in[9];
  const float* vb  = (const float*)d_in[10];
  const float* vcw = (const float*)d_in[11];
  const float* vcb = (const float*)d_in[12];
  const float* oW  = (const float*)d_in[13];
  const float* ob  = (const float*)d_in[14];
  const float* er  = (const float*)d_in[15];
  float* out = (float*)d_out;

  const size_t NE = (size_t)B_ * W_ * C_;  // 4M
  const size_t NW = (size_t)C_ * C_;       // 1M
  short* ws   = (short*)d_ws;
  short* xh    = ws;                        // 4M sh; dead after QKV GEMM -> vt
  short* wqkvh = xh + NE;                   // 3M sh (+oWh contiguous)
  short* oWh   = wqkvh + 3 * NW;            // 1M sh
  short* ertb  = oWh + NW;                  // 64K sh
  short* yqkv  = ertb + (size_t)W_ * D_;    // 12M sh; dead after convs -> oat
  short* qc    = yqkv + (size_t)(B_ * W_) * (3 * C_);
  short* kc    = qc + NE;
  short* vt    = xh;
  short* oat   = yqkv;
  // total = 56.1 MB (< 65.7 MB proven in round 4)

  prep_kernel<<<4160, 256, 0, stream>>>(x, qW, kW, vW, oW, er, xh, wqkvh, ertb);

  const int M = B_ * W_;
  dim3 gq(3 * C_ / 128, M / 128);  // (24, 32) fused QKV
  gemm_bf16_v3<0><<<gq, 256, 0, stream>>>(xh, wqkvh, qb, kb, vb, yqkv, M, 3 * C_, C_);

  dwconv_qk_kernel<<<dim3(2048, 2), 256, 0, stream>>>(yqkv, qcw, qcb, kcw, kcb, qc, kc);
  dwconv_vt_kernel<<<dim3(W_ / 64, B_ * H_), 256, 0, stream>>>(yqkv, vcw, vcb, vt);

  attn_v3_kernel<<<1024, 256, 0, stream>>>(qc, kc, vt, ertb, oat);

  dim3 go(C_ / 128, M / 128);  // (8, 32)
  gemm_bf16_v3<1><<<go, 256, 0, stream>>>(oat, oWh, ob, ob, ob, out, M, C_, C_);
}

// Round 10
// 221.524 us; speedup vs baseline: 5.4705x; 1.0938x over previous
//
#include <hip/hip_runtime.h>

#define B_ 4
#define W_ 1024
#define C_ 1024
#define H_ 16
#define D_ 64

typedef __attribute__((ext_vector_type(8))) short short8;
typedef __attribute__((ext_vector_type(4))) float f32x4;

__device__ __forceinline__ unsigned short f2b(float f) {
  unsigned u = __builtin_bit_cast(unsigned, f);
  unsigned r = (u + 0x7fffu + ((u >> 16) & 1u)) >> 16;
  return (unsigned short)r;
}
__device__ __forceinline__ float b2f(short b) {
  return __builtin_bit_cast(float, ((unsigned)(unsigned short)b) << 16);
}
// T12 recipe: packed f32x2 -> bf16x2 (dst.lo = bf16(a), dst.hi = bf16(b))
__device__ __forceinline__ unsigned pk2(float a, float b) {
  unsigned r;
  asm("v_cvt_pk_bf16_f32 %0, %1, %2" : "=v"(r) : "v"(a), "v"(b));
  return r;
}
// native 2^x (v_exp_f32 IS base-2)
__device__ __forceinline__ float ex2(float x) {
  float r;
  asm("v_exp_f32 %0, %1" : "=v"(r) : "v"(x));
  return r;
}

// async global->LDS, 16B per lane. dst must be wave-uniform base + lane*16.
typedef __attribute__((address_space(1))) void GV;
typedef __attribute__((address_space(3))) void LV;
__device__ __forceinline__ void gl16(const short* g, short* l) {
  __builtin_amdgcn_global_load_lds((GV*)g, (LV*)l, 16, 0, 0);
}

// ---------------------------------------------------------------------------
// prep: x cast (blocks 0..2047), 4 weights cast (2048..4095), er transpose
// (4096..4159). Single dispatch replaces 3.
// ---------------------------------------------------------------------------
__global__ __launch_bounds__(256)
void prep_kernel(const float* __restrict__ x, const float* __restrict__ qW,
                 const float* __restrict__ kW, const float* __restrict__ vW,
                 const float* __restrict__ oW, const float* __restrict__ er,
                 short* __restrict__ xh, short* __restrict__ wh,
                 short* __restrict__ ertb) {
  const int bx = blockIdx.x;
  const int tid = threadIdx.x;
  if (bx < 4096) {
    const float* s;
    short* d;
    size_t u;
    if (bx < 2048) {
      u = (size_t)bx * 256 + tid;
      s = x; d = xh;
    } else {
      u = (size_t)(bx - 2048) * 256 + tid;  // 0..524287 over 4 matrices
      const int w = (int)(u >> 17);
      s = (w == 0) ? qW : (w == 1) ? kW : (w == 2) ? vW : oW;
      d = wh + (u & ~(size_t)131071) * 8;   // contiguous wqkv|oW region
      u &= 131071;
      const float4* p = (const float4*)s + u * 2;
      float4 a = p[0], b = p[1];
      short8 r;
      r[0] = f2b(a.x); r[1] = f2b(a.y); r[2] = f2b(a.z); r[3] = f2b(a.w);
      r[4] = f2b(b.x); r[5] = f2b(b.y); r[6] = f2b(b.z); r[7] = f2b(b.w);
      *((short8*)d + u) = r;
      return;
    }
    const float4* p = (const float4*)s + u * 2;
    float4 a = p[0], b = p[1];
    short8 r;
    r[0] = f2b(a.x); r[1] = f2b(a.y); r[2] = f2b(a.z); r[3] = f2b(a.w);
    r[4] = f2b(b.x); r[5] = f2b(b.y); r[6] = f2b(b.z); r[7] = f2b(b.w);
    *((short8*)d + u) = r;
  } else {
    int i = (bx - 4096) * 256 + tid;  // D * W/4 = 16384
    int d = i >> 8;
    int w4 = (i & 255) << 2;
    float4 v = *(const float4*)(er + (size_t)d * W_ + w4);
    ertb[(size_t)(w4 + 0) * D_ + d] = f2b(v.x);
    ertb[(size_t)(w4 + 1) * D_ + d] = f2b(v.y);
    ertb[(size_t)(w4 + 2) * D_ + d] = f2b(v.z);
    ertb[(size_t)(w4 + 3) * D_ + d] = f2b(v.w);
  }
}

// ---------------------------------------------------------------------------
// GEMM v3: 128x128 tile, BK=64, 2-phase dbuf via counted vmcnt (T3/T4-min),
// T2 both-sides XOR swizzle (inverse-swizzled gl16 source + XOR'd ds_read).
// Raw s_barrier (no vmcnt(0) drain) keeps next tile's loads in flight.
// ---------------------------------------------------------------------------
#define GSTAGE(T, BUF)                                                       \
  {                                                                          \
    const int k0_ = (T) * 64;                                                \
    gl16(ga + (size_t)0  * K + k0_, sA[BUF] + 0    + ldst);                  \
    gl16(gb + (size_t)0  * K + k0_, sB[BUF] + 0    + ldst);                  \
    gl16(ga + (size_t)32 * K + k0_, sA[BUF] + 2048 + ldst);                  \
    gl16(gb + (size_t)32 * K + k0_, sB[BUF] + 2048 + ldst);                  \
    gl16(ga + (size_t)64 * K + k0_, sA[BUF] + 4096 + ldst);                  \
    gl16(gb + (size_t)64 * K + k0_, sB[BUF] + 4096 + ldst);                  \
    gl16(ga + (size_t)96 * K + k0_, sA[BUF] + 6144 + ldst);                  \
    gl16(gb + (size_t)96 * K + k0_, sB[BUF] + 6144 + ldst);                  \
  }

template <int OUTF32>
__global__ __launch_bounds__(256)
void gemm_bf16_v3(const short* __restrict__ A, const short* __restrict__ Wt,
                  const float* __restrict__ b0, const float* __restrict__ b1,
                  const float* __restrict__ b2, void* __restrict__ outv,
                  int M, int N, int K) {
  __shared__ short sA[2][128 * 64];
  __shared__ short sB[2][128 * 64];
  const int tid = threadIdx.x;
  const int bm = blockIdx.y * 128, bn = blockIdx.x * 128;
  const int wv = tid >> 6, lane = tid & 63;
  const int wr = (wv >> 1) * 64, wc = (wv & 1) * 64;
  const int l15 = lane & 15, l4 = lane >> 4;
  const int srow = tid >> 3;                      // staged row 0..31 (of each 32-row group)
  const int swsc = ((tid & 7) ^ (srow & 7)) * 8;  // inverse-swizzled source chunk
  const int cxor = (l15 & 7) * 8;                 // read-side XOR
  const int ldst = tid * 8;                       // linear LDS dest (gl16 requirement)
  const short* ga = A + (size_t)(bm + srow) * K + swsc;
  const short* gb = Wt + (size_t)(bn + srow) * K + swsc;

  f32x4 acc[4][4];
#pragma unroll
  for (int mf = 0; mf < 4; ++mf)
#pragma unroll
    for (int nf = 0; nf < 4; ++nf) acc[mf][nf] = (f32x4){0.f, 0.f, 0.f, 0.f};

  const int nt = K >> 6;
  GSTAGE(0, 0)
  for (int t = 0; t < nt; ++t) {
    const int cur = t & 1;
    if (t + 1 < nt) {
      GSTAGE(t + 1, cur ^ 1)
      asm volatile("s_waitcnt vmcnt(8)" ::: "memory");  // tile t landed; t+1 in flight
    } else {
      asm volatile("s_waitcnt vmcnt(0)" ::: "memory");
    }
    __builtin_amdgcn_s_barrier();
    __builtin_amdgcn_sched_barrier(0);
#pragma unroll
    for (int ks = 0; ks < 2; ++ks) {
      short8 af[4], bf[4];
#pragma unroll
      for (int mf = 0; mf < 4; ++mf)
        af[mf] = *(short8*)(sA[cur] + (wr + mf * 16 + l15) * 64 + ((ks * 32 + l4 * 8) ^ cxor));
#pragma unroll
      for (int nf = 0; nf < 4; ++nf)
        bf[nf] = *(short8*)(sB[cur] + (wc + nf * 16 + l15) * 64 + ((ks * 32 + l4 * 8) ^ cxor));
#pragma unroll
      for (int mf = 0; mf < 4; ++mf)
#pragma unroll
        for (int nf = 0; nf < 4; ++nf)
          acc[mf][nf] = __builtin_amdgcn_mfma_f32_16x16x32_bf16(af[mf], bf[nf], acc[mf][nf], 0, 0, 0);
    }
    __builtin_amdgcn_sched_barrier(0);
    __builtin_amdgcn_s_barrier();  // all waves done reading buf[cur] before t+1 stages into it
  }
#pragma unroll
  for (int mf = 0; mf < 4; ++mf) {
#pragma unroll
    for (int nf = 0; nf < 4; ++nf) {
      const int n = bn + wc + nf * 16 + l15;
      const float bs = (n < 1024) ? b0[n] : ((n < 2048) ? b1[n - 1024] : b2[n - 2048]);
#pragma unroll
      for (int r = 0; r < 4; ++r) {
        const int m = bm + wr + mf * 16 + l4 * 4 + r;
        const float v = acc[mf][nf][r] + bs;
        if (OUTF32) ((float*)outv)[(size_t)m * N + n] = v;
        else        ((short*)outv)[(size_t)m * N + n] = (short)f2b(v);
      }
    }
  }
}

// ---------------------------------------------------------------------------
// Causal depthwise conv K=3 for q,k planes of yqkv (B*W, 3C); y selects plane
// ---------------------------------------------------------------------------
__global__ __launch_bounds__(256)
void dwconv_qk_kernel(const short* __restrict__ yqkv,
                      const float* __restrict__ qcw, const float* __restrict__ qcb,
                      const float* __restrict__ kcw, const float* __restrict__ kcb,
                      short* __restrict__ qc, short* __restrict__ kc) {
  const int t = blockIdx.y;
  const float* cw = t ? kcw : qcw;
  const float* cb = t ? kcb : qcb;
  short* out = t ? kc : qc;
  const int idx = blockIdx.x * 256 + threadIdx.x;  // over B*W*(C/8)
  const int c8 = (idx & (C_ / 8 - 1)) << 3;
  const int bw = idx >> 7;
  const int w = bw & (W_ - 1);
  const short* base = yqkv + (size_t)bw * (3 * C_) + t * C_ + c8;
  short8 x2 = *(const short8*)base;
  short8 x1, x0;
  if (w >= 1) x1 = *(const short8*)(base - 3 * C_); else { for (int j = 0; j < 8; ++j) x1[j] = 0; }
  if (w >= 2) x0 = *(const short8*)(base - 6 * C_); else { for (int j = 0; j < 8; ++j) x0[j] = 0; }
  short8 r;
#pragma unroll
  for (int j = 0; j < 8; ++j) {
    const int c = c8 + j;
    float acc = b2f(x0[j]) * cw[c * 3 + 0] + b2f(x1[j]) * cw[c * 3 + 1] +
                b2f(x2[j]) * cw[c * 3 + 2] + cb[c];
    r[j] = (short)f2b(acc);
  }
  *(short8*)(out + (size_t)bw * C_ + c8) = r;
}

// ---------------------------------------------------------------------------
// V plane: causal dwconv fused with head-transpose. yqkv plane 2 -> vt(B*H,D,W)
// ---------------------------------------------------------------------------
__global__ __launch_bounds__(256)
void dwconv_vt_kernel(const short* __restrict__ yqkv, const float* __restrict__ vcw,
                      const float* __restrict__ vcb, short* __restrict__ vt) {
  __shared__ short t[64][72];
  const int bh = blockIdx.y, w0 = blockIdx.x * 64;
  const int b = bh >> 4, h = bh & 15;
  const int tid = threadIdx.x;
  for (int c = tid; c < 512; c += 256) {
    const int w = c >> 3, dg = c & 7;
    const int gw = w0 + w;
    const short* base = yqkv + ((size_t)(b * W_ + gw)) * (3 * C_) + 2 * C_ + h * 64 + dg * 8;
    short8 x2 = *(const short8*)base;
    short8 x1, x0;
    if (gw >= 1) x1 = *(const short8*)(base - 3 * C_); else { for (int j = 0; j < 8; ++j) x1[j] = 0; }
    if (gw >= 2) x0 = *(const short8*)(base - 6 * C_); else { for (int j = 0; j < 8; ++j) x0[j] = 0; }
#pragma unroll
    for (int j = 0; j < 8; ++j) {
      const int ch = h * 64 + dg * 8 + j;
      float acc = b2f(x0[j]) * vcw[ch * 3 + 0] + b2f(x1[j]) * vcw[ch * 3 + 1] +
                  b2f(x2[j]) * vcw[ch * 3 + 2] + vcb[ch];
      t[dg * 8 + j][w] = (short)f2b(acc);
    }
  }
  __syncthreads();
  for (int c = tid; c < 512; c += 256) {
    const int d = c >> 3, wg = c & 7;
    *(short8*)(vt + ((size_t)(bh * 64 + d)) * W_ + w0 + wg * 8) = *(short8*)&t[d][wg * 8];
  }
}

// ---------------------------------------------------------------------------
// attn v4: QBLK=128, 8 waves (512 thr), KVBLK=64 dbuf (48KB) + sP (16KB).
// Q/Er fragments loaded DIRECTLY global->regs (no LDS staging).
// Counted vmcnt(3) 2-phase staging; exp2-domain online softmax; T2 swizzle.
// ---------------------------------------------------------------------------
__global__ __launch_bounds__(512, 4)
void attn_v4_kernel(const short* __restrict__ q, const short* __restrict__ k,
                    const short* __restrict__ vt, const short* __restrict__ ert,
                    short* __restrict__ o) {
  __shared__ short sK[2][4096];
  __shared__ short sQj[2][4096];
  __shared__ short sVt[2][4096];
  __shared__ short sP[128 * 64];  // 16KB; total 64KB -> 2 blocks/CU, 16 waves

  const int tid = threadIdx.x;
  const int wid = blockIdx.x;                     // 512 blocks
  const int swz = (wid & 7) * 64 + (wid >> 3);    // T1: XCD x -> bh in [8x, 8x+7]
  const int bh = swz >> 3, qt = swz & 7;
  const int b = bh >> 4, h = bh & 15;
  const int i0 = qt * 128;
  const int wv = tid >> 6, lane = tid & 63;       // wv 0..7
  const int l15 = lane & 15, l4 = lane >> 4;
  const size_t bW = (size_t)b * W_;
  const int srow = tid >> 3;                      // 0..63: one gl16 covers a 64x64 tile
  const int swsc = ((tid & 7) ^ (srow & 7)) * 8;  // inverse-swizzled source chunk
  const int cxor = (l15 & 7) * 8;                 // read-side XOR

  const short* qbase = q + bW * C_ + h * 64;
  const short* kbase = k + bW * C_ + h * 64;
  const short* vbase = vt + (size_t)bh * 64 * W_;

  // stage jt=0 (3 outstanding)
  gl16(kbase + (size_t)srow * C_ + swsc, sK[0] + tid * 8);
  gl16(qbase + (size_t)srow * C_ + swsc, sQj[0] + tid * 8);
  gl16(vbase + (size_t)srow * W_ + swsc, sVt[0] + tid * 8);

  // Q / Er fragments straight to registers (natural layout, no XOR)
  short8 bQ[2], bE[2];
  {
    const int qi = i0 + wv * 16 + l15;
#pragma unroll
    for (int ks = 0; ks < 2; ++ks) {
      bQ[ks] = *(const short8*)(qbase + (size_t)qi * C_ + ks * 32 + l4 * 8);
      bE[ks] = *(const short8*)(ert + (size_t)qi * 64 + ks * 32 + l4 * 8);
    }
  }

  float m_ = -1e30f, l_ = 0.f;
  f32x4 accO[4];
#pragma unroll
  for (int mf = 0; mf < 4; ++mf) accO[mf] = (f32x4){0.f, 0.f, 0.f, 0.f};
  const float SC2 = 0.03125f * 1.44269504f;  // (1/sqrt(C))*log2(e): exp2 domain
  const float THR2 = 11.5416f;               // defer-max THR=8 (ln) in log2

  for (int jt = 0; jt < 16; ++jt) {
    const int cur = jt & 1;
    if (jt < 15) {
      const int j0n = (jt + 1) * 64;
      gl16(kbase + (size_t)(j0n + srow) * C_ + swsc, sK[cur ^ 1] + tid * 8);
      gl16(qbase + (size_t)(j0n + srow) * C_ + swsc, sQj[cur ^ 1] + tid * 8);
      gl16(vbase + (size_t)srow * W_ + j0n + swsc, sVt[cur ^ 1] + tid * 8);
      asm volatile("s_waitcnt vmcnt(3)" ::: "memory");  // jt's tiles landed
    } else {
      asm volatile("s_waitcnt vmcnt(0)" ::: "memory");
    }
    __builtin_amdgcn_s_barrier();
    __builtin_amdgcn_sched_barrier(0);

    f32x4 s[4];
#pragma unroll
    for (int mf = 0; mf < 4; ++mf) s[mf] = (f32x4){0.f, 0.f, 0.f, 0.f};
    const int ofA = (l4 * 8) ^ cxor;
    const int ofB = (32 + l4 * 8) ^ cxor;
    __builtin_amdgcn_s_setprio(1);
#pragma unroll
    for (int mf = 0; mf < 4; ++mf) {
      const short* kp = sK[cur] + (mf * 16 + l15) * 64;
      const short* jp = sQj[cur] + (mf * 16 + l15) * 64;
      s[mf] = __builtin_amdgcn_mfma_f32_16x16x32_bf16(*(short8*)(kp + ofA), bQ[0], s[mf], 0, 0, 0);
      s[mf] = __builtin_amdgcn_mfma_f32_16x16x32_bf16(*(short8*)(kp + ofB), bQ[1], s[mf], 0, 0, 0);
      s[mf] = __builtin_amdgcn_mfma_f32_16x16x32_bf16(*(short8*)(jp + ofA), bE[0], s[mf], 0, 0, 0);
      s[mf] = __builtin_amdgcn_mfma_f32_16x16x32_bf16(*(short8*)(jp + ofB), bE[1], s[mf], 0, 0, 0);
    }
    __builtin_amdgcn_s_setprio(0);

    float px = fmaxf(fmaxf(s[0][0], s[0][1]), fmaxf(s[0][2], s[0][3]));
#pragma unroll
    for (int mf = 1; mf < 4; ++mf)
      px = fmaxf(px, fmaxf(fmaxf(s[mf][0], s[mf][1]), fmaxf(s[mf][2], s[mf][3])));
    px = fmaxf(px, __shfl_xor(px, 16));
    px = fmaxf(px, __shfl_xor(px, 32));
    px *= SC2;
    if (!__all(px <= m_ + THR2)) {  // T13 defer-max
      const float mn = fmaxf(m_, px);
      const float sc = ex2(m_ - mn);
      l_ *= sc;
#pragma unroll
      for (int mf = 0; mf < 4; ++mf)
#pragma unroll
        for (int r = 0; r < 4; ++r) accO[mf][r] *= sc;
      m_ = mn;
    }
    float p[4][4];
    float rs = 0.f;
#pragma unroll
    for (int mf = 0; mf < 4; ++mf)
#pragma unroll
      for (int r = 0; r < 4; ++r) {
        p[mf][r] = ex2(__builtin_fmaf(s[mf][r], SC2, -m_));
        rs += p[mf][r];
      }
    rs += __shfl_xor(rs, 16);
    rs += __shfl_xor(rs, 32);
    l_ += rs;

    // sP swizzled write: row (wv*16+l15) in 0..127, pitch 64
#pragma unroll
    for (int mf = 0; mf < 4; ++mf) {
      uint2 w2;
      w2.x = pk2(p[mf][0], p[mf][1]);
      w2.y = pk2(p[mf][2], p[mf][3]);
      const int off = (((2 * mf + (l4 >> 1)) ^ (l15 & 7)) * 8) + (l4 & 1) * 4;
      *(uint2*)(sP + (wv * 16 + l15) * 64 + off) = w2;
    }

    short8 pf[2];
#pragma unroll
    for (int ks = 0; ks < 2; ++ks)
      pf[ks] = *(short8*)(sP + (wv * 16 + l15) * 64 + ((ks * 32 + l4 * 8) ^ cxor));
    __builtin_amdgcn_s_setprio(1);
#pragma unroll
    for (int mf = 0; mf < 4; ++mf) {
      const short* vp = sVt[cur] + (mf * 16 + l15) * 64;
      accO[mf] = __builtin_amdgcn_mfma_f32_16x16x32_bf16(*(short8*)(vp + ofA), pf[0], accO[mf], 0, 0, 0);
      accO[mf] = __builtin_amdgcn_mfma_f32_16x16x32_bf16(*(short8*)(vp + ofB), pf[1], accO[mf], 0, 0, 0);
    }
    __builtin_amdgcn_s_setprio(0);

    __builtin_amdgcn_sched_barrier(0);
    __builtin_amdgcn_s_barrier();  // all waves done with buf[cur] before restage
  }

  const float inv = 1.f / l_;
  const size_t orow = (bW + i0 + wv * 16 + l15) * C_ + h * 64;
#pragma unroll
  for (int mf = 0; mf < 4; ++mf) {
    uint2 w2;
    w2.x = pk2(accO[mf][0] * inv, accO[mf][1] * inv);
    w2.y = pk2(accO[mf][2] * inv, accO[mf][3] * inv);
    *(uint2*)(o + orow + mf * 16 + l4 * 4) = w2;
  }
}

// ---------------------------------------------------------------------------
extern "C" void kernel_launch(void* const* d_in, const int* in_sizes, int n_in,
                              void* d_out, int out_size, void* d_ws, size_t ws_size,
                              hipStream_t stream) {
  (void)in_sizes; (void)n_in; (void)out_size; (void)ws_size;
  const float* x   = (const float*)d_in[0];
  const float* qW  = (const float*)d_in[1];
  const float* qb  = (const float*)d_in[2];
  const float* qcw = (const float*)d_in[3];
  const float* qcb = (const float*)d_in[4];
  const float* kW  = (const float*)d_in[5];
  const float* kb  = (const float*)d_in[6];
  const float* kcw = (const float*)d_in[7];
  const float* kcb = (const float*)d_in[8];
  const float* vW  = (const float*)d_in[9];
  const float* vb  = (const float*)d_in[10];
  const float* vcw = (const float*)d_in[11];
  const float* vcb = (const float*)d_in[12];
  const float* oW  = (const float*)d_in[13];
  const float* ob  = (const float*)d_in[14];
  const float* er  = (const float*)d_in[15];
  float* out = (float*)d_out;

  const size_t NE = (size_t)B_ * W_ * C_;  // 4M
  const size_t NW = (size_t)C_ * C_;       // 1M
  short* ws   = (short*)d_ws;
  short* xh    = ws;                        // 4M sh; dead after QKV GEMM -> vt
  short* wqkvh = xh + NE;                   // 3M sh (+oWh contiguous)
  short* oWh   = wqkvh + 3 * NW;            // 1M sh
  short* ertb  = oWh + NW;                  // 64K sh
  short* yqkv  = ertb + (size_t)W_ * D_;    // 12M sh; dead after convs -> oat
  short* qc    = yqkv + (size_t)(B_ * W_) * (3 * C_);
  short* kc    = qc + NE;
  short* vt    = xh;
  short* oat   = yqkv;
  // total = 56.1 MB

  prep_kernel<<<4160, 256, 0, stream>>>(x, qW, kW, vW, oW, er, xh, wqkvh, ertb);

  const int M = B_ * W_;
  dim3 gq(3 * C_ / 128, M / 128);  // (24, 32) fused QKV
  gemm_bf16_v3<0><<<gq, 256, 0, stream>>>(xh, wqkvh, qb, kb, vb, yqkv, M, 3 * C_, C_);

  dwconv_qk_kernel<<<dim3(2048, 2), 256, 0, stream>>>(yqkv, qcw, qcb, kcw, kcb, qc, kc);
  dwconv_vt_kernel<<<dim3(W_ / 64, B_ * H_), 256, 0, stream>>>(yqkv, vcw, vcb, vt);

  attn_v4_kernel<<<512, 512, 0, stream>>>(qc, kc, vt, ertb, oat);

  dim3 go(C_ / 128, M / 128);  // (8, 32)
  gemm_bf16_v3<1><<<go, 256, 0, stream>>>(oat, oWh, ob, ob, ob, out, M, C_, C_);
}

// Round 12
// 215.624 us; speedup vs baseline: 5.6202x; 1.0274x over previous
//
#include <hip/hip_runtime.h>

#define B_ 4
#define W_ 1024
#define C_ 1024
#define H_ 16
#define D_ 64

typedef __attribute__((ext_vector_type(8))) short short8;
typedef __attribute__((ext_vector_type(4))) float f32x4;

__device__ __forceinline__ unsigned short f2b(float f) {
  unsigned u = __builtin_bit_cast(unsigned, f);
  unsigned r = (u + 0x7fffu + ((u >> 16) & 1u)) >> 16;
  return (unsigned short)r;
}
__device__ __forceinline__ float b2f(short b) {
  return __builtin_bit_cast(float, ((unsigned)(unsigned short)b) << 16);
}
// T12 recipe: packed f32x2 -> bf16x2 (dst.lo = bf16(a), dst.hi = bf16(b))
__device__ __forceinline__ unsigned pk2(float a, float b) {
  unsigned r;
  asm("v_cvt_pk_bf16_f32 %0, %1, %2" : "=v"(r) : "v"(a), "v"(b));
  return r;
}
// native 2^x (v_exp_f32 IS base-2)
__device__ __forceinline__ float ex2(float x) {
  float r;
  asm("v_exp_f32 %0, %1" : "=v"(r) : "v"(x));
  return r;
}

// async global->LDS, 16B per lane. dst must be wave-uniform base + lane*16.
typedef __attribute__((address_space(1))) void GV;
typedef __attribute__((address_space(3))) void LV;
__device__ __forceinline__ void gl16(const short* g, short* l) {
  __builtin_amdgcn_global_load_lds((GV*)g, (LV*)l, 16, 0, 0);
}

// ---------------------------------------------------------------------------
// prep: x cast (blocks 0..2047), 4 weights cast (2048..4095), er transpose
// (4096..4159).
// ---------------------------------------------------------------------------
__global__ __launch_bounds__(256)
void prep_kernel(const float* __restrict__ x, const float* __restrict__ qW,
                 const float* __restrict__ kW, const float* __restrict__ vW,
                 const float* __restrict__ oW, const float* __restrict__ er,
                 short* __restrict__ xh, short* __restrict__ wh,
                 short* __restrict__ ertb) {
  const int bx = blockIdx.x;
  const int tid = threadIdx.x;
  if (bx < 4096) {
    const float* s;
    short* d;
    size_t u;
    if (bx < 2048) {
      u = (size_t)bx * 256 + tid;
      s = x; d = xh;
    } else {
      u = (size_t)(bx - 2048) * 256 + tid;  // 0..524287 over 4 matrices
      const int w = (int)(u >> 17);
      s = (w == 0) ? qW : (w == 1) ? kW : (w == 2) ? vW : oW;
      d = wh + (u & ~(size_t)131071) * 8;   // contiguous wqkv|oW region
      u &= 131071;
      const float4* p = (const float4*)s + u * 2;
      float4 a = p[0], b = p[1];
      short8 r;
      r[0] = f2b(a.x); r[1] = f2b(a.y); r[2] = f2b(a.z); r[3] = f2b(a.w);
      r[4] = f2b(b.x); r[5] = f2b(b.y); r[6] = f2b(b.z); r[7] = f2b(b.w);
      *((short8*)d + u) = r;
      return;
    }
    const float4* p = (const float4*)s + u * 2;
    float4 a = p[0], b = p[1];
    short8 r;
    r[0] = f2b(a.x); r[1] = f2b(a.y); r[2] = f2b(a.z); r[3] = f2b(a.w);
    r[4] = f2b(b.x); r[5] = f2b(b.y); r[6] = f2b(b.z); r[7] = f2b(b.w);
    *((short8*)d + u) = r;
  } else {
    int i = (bx - 4096) * 256 + tid;  // D * W/4 = 16384
    int d = i >> 8;
    int w4 = (i & 255) << 2;
    float4 v = *(const float4*)(er + (size_t)d * W_ + w4);
    ertb[(size_t)(w4 + 0) * D_ + d] = f2b(v.x);
    ertb[(size_t)(w4 + 1) * D_ + d] = f2b(v.y);
    ertb[(size_t)(w4 + 2) * D_ + d] = f2b(v.z);
    ertb[(size_t)(w4 + 3) * D_ + d] = f2b(v.w);
  }
}

// ---------------------------------------------------------------------------
// GEMM v4b: 128x128 tile, BK=32, 2-phase dbuf, counted vmcnt(4), 32KB LDS ->
// 3 blocks/CU co-resident (grid 768 = 3x256, no tail).
// Chunk swizzle f(row)=(row>>1)&3 (64B rows span only 16 banks; without this
// a quarter-phase of the fragment read is 8-way bank-conflicted; with it 2-way
// = free per m136). Inverse-swizzled gl16 SOURCE + same XOR on reads (rule #21).
// ---------------------------------------------------------------------------
#define GSTAGE32(T, BUF)                                                     \
  {                                                                          \
    const int k0_ = (T) * 32;                                                \
    gl16(ga + (size_t)0  * K + k0_, sA[BUF] + ldst);                         \
    gl16(gb + (size_t)0  * K + k0_, sB[BUF] + ldst);                         \
    gl16(ga + (size_t)64 * K + k0_, sA[BUF] + 2048 + ldst);                  \
    gl16(gb + (size_t)64 * K + k0_, sB[BUF] + 2048 + ldst);                  \
  }

template <int OUTF32>
__global__ __launch_bounds__(256)
void gemm_bf16_v4(const short* __restrict__ A, const short* __restrict__ Wt,
                  const float* __restrict__ b0, const float* __restrict__ b1,
                  const float* __restrict__ b2, void* __restrict__ outv,
                  int M, int N, int K) {
  __shared__ short sA[2][128 * 32];
  __shared__ short sB[2][128 * 32];
  const int tid = threadIdx.x;
  const int bm = blockIdx.y * 128, bn = blockIdx.x * 128;
  const int wv = tid >> 6, lane = tid & 63;
  const int wr = (wv >> 1) * 64, wc = (wv & 1) * 64;
  const int l15 = lane & 15, l4 = lane >> 4;
  const int srow = tid >> 2;       // 0..63
  const int swsc = ((tid & 3) ^ ((srow >> 1) & 3)) * 8;  // inv-swizzled src chunk
  const int rxor = ((l15 >> 1) & 3) * 8;                 // read-side XOR (shorts)
  const int ldst = tid * 8;        // linear LDS dest (gl16 requirement)
  const short* ga = A + (size_t)(bm + srow) * K + swsc;
  const short* gb = Wt + (size_t)(bn + srow) * K + swsc;

  f32x4 acc[4][4];
#pragma unroll
  for (int mf = 0; mf < 4; ++mf)
#pragma unroll
    for (int nf = 0; nf < 4; ++nf) acc[mf][nf] = (f32x4){0.f, 0.f, 0.f, 0.f};

  const int nt = K >> 5;
  GSTAGE32(0, 0)
  for (int t = 0; t < nt; ++t) {
    const int cur = t & 1;
    if (t + 1 < nt) {
      GSTAGE32(t + 1, cur ^ 1)
      asm volatile("s_waitcnt vmcnt(4)" ::: "memory");  // tile t landed; t+1 in flight
    } else {
      asm volatile("s_waitcnt vmcnt(0)" ::: "memory");
    }
    __builtin_amdgcn_s_barrier();
    __builtin_amdgcn_sched_barrier(0);
    short8 af[4], bf[4];
#pragma unroll
    for (int mf = 0; mf < 4; ++mf)
      af[mf] = *(short8*)(sA[cur] + (wr + mf * 16 + l15) * 32 + ((l4 * 8) ^ rxor));
#pragma unroll
    for (int nf = 0; nf < 4; ++nf)
      bf[nf] = *(short8*)(sB[cur] + (wc + nf * 16 + l15) * 32 + ((l4 * 8) ^ rxor));
#pragma unroll
    for (int mf = 0; mf < 4; ++mf)
#pragma unroll
      for (int nf = 0; nf < 4; ++nf)
        acc[mf][nf] = __builtin_amdgcn_mfma_f32_16x16x32_bf16(af[mf], bf[nf], acc[mf][nf], 0, 0, 0);
    __builtin_amdgcn_sched_barrier(0);
    __builtin_amdgcn_s_barrier();  // all waves done reading buf[cur] before restage
  }
#pragma unroll
  for (int mf = 0; mf < 4; ++mf) {
#pragma unroll
    for (int nf = 0; nf < 4; ++nf) {
      const int n = bn + wc + nf * 16 + l15;
      const float bs = (n < 1024) ? b0[n] : ((n < 2048) ? b1[n - 1024] : b2[n - 2048]);
#pragma unroll
      for (int r = 0; r < 4; ++r) {
        const int m = bm + wr + mf * 16 + l4 * 4 + r;
        const float v = acc[mf][nf][r] + bs;
        if (OUTF32) ((float*)outv)[(size_t)m * N + n] = v;
        else        ((short*)outv)[(size_t)m * N + n] = (short)f2b(v);
      }
    }
  }
}

// ---------------------------------------------------------------------------
// Merged causal dwconv: blocks 0..2047 q-plane, 2048..4095 k-plane,
// 4096..5119 v-plane fused with head-transpose -> vt(B*H,D,W).
// ---------------------------------------------------------------------------
__global__ __launch_bounds__(256)
void dwconv_all_kernel(const short* __restrict__ yqkv,
                       const float* __restrict__ qcw, const float* __restrict__ qcb,
                       const float* __restrict__ kcw, const float* __restrict__ kcb,
                       const float* __restrict__ vcw, const float* __restrict__ vcb,
                       short* __restrict__ qc, short* __restrict__ kc,
                       short* __restrict__ vt) {
  __shared__ short t_[64][72];
  const int bx = blockIdx.x;
  const int tid = threadIdx.x;
  if (bx < 4096) {
    const int t = bx >> 11;  // 0: q, 1: k
    const float* cw = t ? kcw : qcw;
    const float* cb = t ? kcb : qcb;
    short* out = t ? kc : qc;
    const int idx = (bx & 2047) * 256 + tid;
    const int c8 = (idx & (C_ / 8 - 1)) << 3;
    const int bw = idx >> 7;
    const int w = bw & (W_ - 1);
    const short* base = yqkv + (size_t)bw * (3 * C_) + t * C_ + c8;
    short8 x2 = *(const short8*)base;
    short8 x1, x0;
    if (w >= 1) x1 = *(const short8*)(base - 3 * C_); else { for (int j = 0; j < 8; ++j) x1[j] = 0; }
    if (w >= 2) x0 = *(const short8*)(base - 6 * C_); else { for (int j = 0; j < 8; ++j) x0[j] = 0; }
    short8 r;
#pragma unroll
    for (int j = 0; j < 8; ++j) {
      const int c = c8 + j;
      float acc = b2f(x0[j]) * cw[c * 3 + 0] + b2f(x1[j]) * cw[c * 3 + 1] +
                  b2f(x2[j]) * cw[c * 3 + 2] + cb[c];
      r[j] = (short)f2b(acc);
    }
    *(short8*)(out + (size_t)bw * C_ + c8) = r;
  } else {
    const int bx2 = bx - 4096;
    const int w0 = (bx2 & 15) * 64, bh = bx2 >> 4;
    const int b = bh >> 4, h = bh & 15;
    for (int c = tid; c < 512; c += 256) {
      const int w = c >> 3, dg = c & 7;
      const int gw = w0 + w;
      const short* base = yqkv + ((size_t)(b * W_ + gw)) * (3 * C_) + 2 * C_ + h * 64 + dg * 8;
      short8 x2 = *(const short8*)base;
      short8 x1, x0;
      if (gw >= 1) x1 = *(const short8*)(base - 3 * C_); else { for (int j = 0; j < 8; ++j) x1[j] = 0; }
      if (gw >= 2) x0 = *(const short8*)(base - 6 * C_); else { for (int j = 0; j < 8; ++j) x0[j] = 0; }
#pragma unroll
      for (int j = 0; j < 8; ++j) {
        const int ch = h * 64 + dg * 8 + j;
        float acc = b2f(x0[j]) * vcw[ch * 3 + 0] + b2f(x1[j]) * vcw[ch * 3 + 1] +
                    b2f(x2[j]) * vcw[ch * 3 + 2] + vcb[ch];
        t_[dg * 8 + j][w] = (short)f2b(acc);
      }
    }
    __syncthreads();
    for (int c = tid; c < 512; c += 256) {
      const int d = c >> 3, wg = c & 7;
      *(short8*)(vt + ((size_t)(bh * 64 + d)) * W_ + w0 + wg * 8) = *(short8*)&t_[d][wg * 8];
    }
  }
}

// ---------------------------------------------------------------------------
// attn v4: QBLK=128, 8 waves (512 thr), KVBLK=64 dbuf (48KB) + sP (16KB).
// Q/Er fragments loaded DIRECTLY global->regs (no LDS staging).
// Counted vmcnt(3) 2-phase staging; exp2-domain online softmax; T2 swizzle.
// ---------------------------------------------------------------------------
__global__ __launch_bounds__(512, 4)
void attn_v4_kernel(const short* __restrict__ q, const short* __restrict__ k,
                    const short* __restrict__ vt, const short* __restrict__ ert,
                    short* __restrict__ o) {
  __shared__ short sK[2][4096];
  __shared__ short sQj[2][4096];
  __shared__ short sVt[2][4096];
  __shared__ short sP[128 * 64];  // 16KB; total 64KB -> 2 blocks/CU, 16 waves

  const int tid = threadIdx.x;
  const int wid = blockIdx.x;                     // 512 blocks
  const int swz = (wid & 7) * 64 + (wid >> 3);    // T1: XCD x -> bh in [8x, 8x+7]
  const int bh = swz >> 3, qt = swz & 7;
  const int b = bh >> 4, h = bh & 15;
  const int i0 = qt * 128;
  const int wv = tid >> 6, lane = tid & 63;       // wv 0..7
  const int l15 = lane & 15, l4 = lane >> 4;
  const size_t bW = (size_t)b * W_;
  const int srow = tid >> 3;                      // 0..63: one gl16 covers a 64x64 tile
  const int swsc = ((tid & 7) ^ (srow & 7)) * 8;  // inverse-swizzled source chunk
  const int cxor = (l15 & 7) * 8;                 // read-side XOR

  const short* qbase = q + bW * C_ + h * 64;
  const short* kbase = k + bW * C_ + h * 64;
  const short* vbase = vt + (size_t)bh * 64 * W_;

  // stage jt=0 (3 outstanding)
  gl16(kbase + (size_t)srow * C_ + swsc, sK[0] + tid * 8);
  gl16(qbase + (size_t)srow * C_ + swsc, sQj[0] + tid * 8);
  gl16(vbase + (size_t)srow * W_ + swsc, sVt[0] + tid * 8);

  // Q / Er fragments straight to registers (natural layout, no XOR)
  short8 bQ[2], bE[2];
  {
    const int qi = i0 + wv * 16 + l15;
#pragma unroll
    for (int ks = 0; ks < 2; ++ks) {
      bQ[ks] = *(const short8*)(qbase + (size_t)qi * C_ + ks * 32 + l4 * 8);
      bE[ks] = *(const short8*)(ert + (size_t)qi * 64 + ks * 32 + l4 * 8);
    }
  }

  float m_ = -1e30f, l_ = 0.f;
  f32x4 accO[4];
#pragma unroll
  for (int mf = 0; mf < 4; ++mf) accO[mf] = (f32x4){0.f, 0.f, 0.f, 0.f};
  const float SC2 = 0.03125f * 1.44269504f;  // (1/sqrt(C))*log2(e): exp2 domain
  const float THR2 = 11.5416f;               // defer-max THR=8 (ln) in log2

  for (int jt = 0; jt < 16; ++jt) {
    const int cur = jt & 1;
    if (jt < 15) {
      const int j0n = (jt + 1) * 64;
      gl16(kbase + (size_t)(j0n + srow) * C_ + swsc, sK[cur ^ 1] + tid * 8);
      gl16(qbase + (size_t)(j0n + srow) * C_ + swsc, sQj[cur ^ 1] + tid * 8);
      gl16(vbase + (size_t)srow * W_ + j0n + swsc, sVt[cur ^ 1] + tid * 8);
      asm volatile("s_waitcnt vmcnt(3)" ::: "memory");  // jt's tiles landed
    } else {
      asm volatile("s_waitcnt vmcnt(0)" ::: "memory");
    }
    __builtin_amdgcn_s_barrier();
    __builtin_amdgcn_sched_barrier(0);

    f32x4 s[4];
#pragma unroll
    for (int mf = 0; mf < 4; ++mf) s[mf] = (f32x4){0.f, 0.f, 0.f, 0.f};
    const int ofA = (l4 * 8) ^ cxor;
    const int ofB = (32 + l4 * 8) ^ cxor;
    __builtin_amdgcn_s_setprio(1);
#pragma unroll
    for (int mf = 0; mf < 4; ++mf) {
      const short* kp = sK[cur] + (mf * 16 + l15) * 64;
      const short* jp = sQj[cur] + (mf * 16 + l15) * 64;
      s[mf] = __builtin_amdgcn_mfma_f32_16x16x32_bf16(*(short8*)(kp + ofA), bQ[0], s[mf], 0, 0, 0);
      s[mf] = __builtin_amdgcn_mfma_f32_16x16x32_bf16(*(short8*)(kp + ofB), bQ[1], s[mf], 0, 0, 0);
      s[mf] = __builtin_amdgcn_mfma_f32_16x16x32_bf16(*(short8*)(jp + ofA), bE[0], s[mf], 0, 0, 0);
      s[mf] = __builtin_amdgcn_mfma_f32_16x16x32_bf16(*(short8*)(jp + ofB), bE[1], s[mf], 0, 0, 0);
    }
    __builtin_amdgcn_s_setprio(0);

    float px = fmaxf(fmaxf(s[0][0], s[0][1]), fmaxf(s[0][2], s[0][3]));
#pragma unroll
    for (int mf = 1; mf < 4; ++mf)
      px = fmaxf(px, fmaxf(fmaxf(s[mf][0], s[mf][1]), fmaxf(s[mf][2], s[mf][3])));
    px = fmaxf(px, __shfl_xor(px, 16));
    px = fmaxf(px, __shfl_xor(px, 32));
    px *= SC2;
    if (!__all(px <= m_ + THR2)) {  // T13 defer-max
      const float mn = fmaxf(m_, px);
      const float sc = ex2(m_ - mn);
      l_ *= sc;
#pragma unroll
      for (int mf = 0; mf < 4; ++mf)
#pragma unroll
        for (int r = 0; r < 4; ++r) accO[mf][r] *= sc;
      m_ = mn;
    }
    float p[4][4];
    float rs = 0.f;
#pragma unroll
    for (int mf = 0; mf < 4; ++mf)
#pragma unroll
      for (int r = 0; r < 4; ++r) {
        p[mf][r] = ex2(__builtin_fmaf(s[mf][r], SC2, -m_));
        rs += p[mf][r];
      }
    rs += __shfl_xor(rs, 16);
    rs += __shfl_xor(rs, 32);
    l_ += rs;

    // sP swizzled write: row (wv*16+l15) in 0..127, pitch 64
#pragma unroll
    for (int mf = 0; mf < 4; ++mf) {
      uint2 w2;
      w2.x = pk2(p[mf][0], p[mf][1]);
      w2.y = pk2(p[mf][2], p[mf][3]);
      const int off = (((2 * mf + (l4 >> 1)) ^ (l15 & 7)) * 8) + (l4 & 1) * 4;
      *(uint2*)(sP + (wv * 16 + l15) * 64 + off) = w2;
    }

    short8 pf[2];
#pragma unroll
    for (int ks = 0; ks < 2; ++ks)
      pf[ks] = *(short8*)(sP + (wv * 16 + l15) * 64 + ((ks * 32 + l4 * 8) ^ cxor));
    __builtin_amdgcn_s_setprio(1);
#pragma unroll
    for (int mf = 0; mf < 4; ++mf) {
      const short* vp = sVt[cur] + (mf * 16 + l15) * 64;
      accO[mf] = __builtin_amdgcn_mfma_f32_16x16x32_bf16(*(short8*)(vp + ofA), pf[0], accO[mf], 0, 0, 0);
      accO[mf] = __builtin_amdgcn_mfma_f32_16x16x32_bf16(*(short8*)(vp + ofB), pf[1], accO[mf], 0, 0, 0);
    }
    __builtin_amdgcn_s_setprio(0);

    __builtin_amdgcn_sched_barrier(0);
    __builtin_amdgcn_s_barrier();  // all waves done with buf[cur] before restage
  }

  const float inv = 1.f / l_;
  const size_t orow = (bW + i0 + wv * 16 + l15) * C_ + h * 64;
#pragma unroll
  for (int mf = 0; mf < 4; ++mf) {
    uint2 w2;
    w2.x = pk2(accO[mf][0] * inv, accO[mf][1] * inv);
    w2.y = pk2(accO[mf][2] * inv, accO[mf][3] * inv);
    *(uint2*)(o + orow + mf * 16 + l4 * 4) = w2;
  }
}

// ---------------------------------------------------------------------------
extern "C" void kernel_launch(void* const* d_in, const int* in_sizes, int n_in,
                              void* d_out, int out_size, void* d_ws, size_t ws_size,
                              hipStream_t stream) {
  (void)in_sizes; (void)n_in; (void)out_size; (void)ws_size;
  const float* x   = (const float*)d_in[0];
  const float* qW  = (const float*)d_in[1];
  const float* qb  = (const float*)d_in[2];
  const float* qcw = (const float*)d_in[3];
  const float* qcb = (const float*)d_in[4];
  const float* kW  = (const float*)d_in[5];
  const float* kb  = (const float*)d_in[6];
  const float* kcw = (const float*)d_in[7];
  const float* kcb = (const float*)d_in[8];
  const float* vW  = (const float*)d_in[9];
  const float* vb  = (const float*)d_in[10];
  const float* vcw = (const float*)d_in[11];
  const float* vcb = (const float*)d_in[12];
  const float* oW  = (const float*)d_in[13];
  const float* ob  = (const float*)d_in[14];
  const float* er  = (const float*)d_in[15];
  float* out = (float*)d_out;

  const size_t NE = (size_t)B_ * W_ * C_;  // 4M
  const size_t NW = (size_t)C_ * C_;       // 1M
  short* ws   = (short*)d_ws;
  short* xh    = ws;                        // 4M sh; dead after QKV GEMM -> vt
  short* wqkvh = xh + NE;                   // 3M sh (+oWh contiguous)
  short* oWh   = wqkvh + 3 * NW;            // 1M sh
  short* ertb  = oWh + NW;                  // 64K sh
  short* yqkv  = ertb + (size_t)W_ * D_;    // 12M sh; dead after convs -> oat
  short* qc    = yqkv + (size_t)(B_ * W_) * (3 * C_);
  short* kc    = qc + NE;
  short* vt    = xh;
  short* oat   = yqkv;
  // total = 56.1 MB

  prep_kernel<<<4160, 256, 0, stream>>>(x, qW, kW, vW, oW, er, xh, wqkvh, ertb);

  const int M = B_ * W_;
  dim3 gq(3 * C_ / 128, M / 128);  // (24, 32) fused QKV
  gemm_bf16_v4<0><<<gq, 256, 0, stream>>>(xh, wqkvh, qb, kb, vb, yqkv, M, 3 * C_, C_);

  dwconv_all_kernel<<<5120, 256, 0, stream>>>(yqkv, qcw, qcb, kcw, kcb, vcw, vcb,
                                              qc, kc, vt);

  attn_v4_kernel<<<512, 512, 0, stream>>>(qc, kc, vt, ertb, oat);

  dim3 go(C_ / 128, M / 128);  // (8, 32)
  gemm_bf16_v4<1><<<go, 256, 0, stream>>>(oat, oWh, ob, ob, ob, out, M, C_, C_);
}